// Round 4
// baseline (2037.452 us; speedup 1.0000x reference)
//
#include <hip/hip_runtime.h>

// GCN 3-layer: N=100000, E=3200000, 128 -> 256 -> 256 -> 40
// Round 11: XCD feature-sharded gathers. Tables stored column-blocked
// [slice][row][SW]; block processes slice blockIdx%NSL so each XCD's L2 only
// sees ONE slice (3.2-6.4MB -> L2-resident; was 25.6MB @ ~16% hit). Wave
// processes 8 edges per VMEM instr (8 lanes x 4-8B), indices/scales stay in
// SGPRs (scalar CSR walk) and reach lanes via cndmask select trees -- no shfl,
// no LDS (r2's failure mode). Cross-group reduce = 3 shfl_xor per row.
// r3's 2-stage load rotation kept. Attacks the CU miss-slot x latency cap
// (r1-r3 bracketed: not VALU, not VMEM-issue, not per-wave depth).

#define NN   100000
#define NE   3200000
#define FIN  128
#define FH   256
#define FOUT 40
#define EPSV 1e-5f

#define BSH   7
#define NBKT  ((NN + 127) >> BSH)  // 782
#define CAPB  8192
#define CHNK  4096

typedef __attribute__((ext_vector_type(8))) short bf8;
typedef __attribute__((ext_vector_type(4))) float f32x4;

__device__ __forceinline__ unsigned short f2bf(float x) {
    unsigned int u = __float_as_uint(x);
    unsigned int r = u + 0x7fffu + ((u >> 16) & 1u);
    return (unsigned short)(r >> 16);
}
__device__ __forceinline__ float bf2f(unsigned short h) {
    return __uint_as_float(((unsigned int)h) << 16);
}
__device__ __forceinline__ void f2bf2(float x, unsigned short& hi, unsigned short& lo) {
    unsigned short h = f2bf(x);
    hi = h;
    lo = f2bf(x - bf2f(h));
}
__device__ __forceinline__ float ub(unsigned int u, int k) {
    return (float)((u >> (8 * k)) & 0xffu);
}
__device__ __forceinline__ float sbyte(unsigned int u, int k) {
    return (float)(int)(signed char)((u >> (8 * k)) & 0xffu);
}

// ---- pass 1: bin edges by dst>>7 into fixed-slot staging (flag computed inline) ----
__global__ __launch_bounds__(256) void k_bin(const int* __restrict__ ei,
                                             int* __restrict__ gcur,
                                             unsigned int* __restrict__ staging) {
    __shared__ int hcnt[NBKT];
    __shared__ int hbase[NBKT];
    __shared__ int sflag;
    const int tid = threadIdx.x;
    const int e0 = blockIdx.x * CHNK;
    for (int b = tid; b < NBKT; b += 256) hcnt[b] = 0;
    if (tid == 0) {
        int zz = 0;
        for (int i = 0; i < 64; i++) zz |= ei[2 * i + 1];
        sflag = (zz == 0) ? 1 : 0;
    }
    __syncthreads();
    const int f = sflag;
    for (int r = 0; r < CHNK / 256; r++) {
        int e = e0 + r * 256 + tid;
        if (e < NE) {
            int d = f ? ei[2 * (NE + e)] : ei[NE + e];
            atomicAdd(&hcnt[d >> BSH], 1);
        }
    }
    __syncthreads();
    for (int b = tid; b < NBKT; b += 256) {
        int c = hcnt[b];
        hbase[b] = c ? atomicAdd(&gcur[b], c) : 0;
    }
    __syncthreads();
    for (int b = tid; b < NBKT; b += 256) hcnt[b] = 0;
    __syncthreads();
    for (int r = 0; r < CHNK / 256; r++) {
        int e = e0 + r * 256 + tid;
        if (e < NE) {
            int s = f ? ei[2 * e] : ei[e];
            int d = f ? ei[2 * (NE + e)] : ei[NE + e];
            int b = d >> BSH;
            int loc = atomicAdd(&hcnt[b], 1);
            int pos = hbase[b] + loc;
            if (pos < CAPB)
                staging[(size_t)b * CAPB + pos] =
                    (unsigned int)s | ((unsigned int)(d & 127) << 17);
        }
    }
}

__global__ void k_bucketscan(const int* __restrict__ gcur, int* __restrict__ bbase) {
    __shared__ int sb2[2][256];
    int t = threadIdx.x;
    int base = t * 4;
    int v0 = (base + 0 < NBKT) ? gcur[base + 0] : 0;
    int v1 = (base + 1 < NBKT) ? gcur[base + 1] : 0;
    int v2 = (base + 2 < NBKT) ? gcur[base + 2] : 0;
    int v3 = (base + 3 < NBKT) ? gcur[base + 3] : 0;
    int s0 = v0, s1 = s0 + v1, s2 = s1 + v2, s3 = s2 + v3;
    sb2[0][t] = s3;
    __syncthreads();
    int pi = 0;
    for (int off = 1; off < 256; off <<= 1) {
        int x = sb2[pi][t];
        if (t >= off) x += sb2[pi][t - off];
        sb2[pi ^ 1][t] = x;
        __syncthreads();
        pi ^= 1;
    }
    int excl = sb2[pi][t] - s3;
    if (base + 0 < NBKT) bbase[base + 0] = excl;
    if (base + 1 < NBKT) bbase[base + 1] = excl + s0;
    if (base + 2 < NBKT) bbase[base + 2] = excl + s1;
    if (base + 3 < NBKT) bbase[base + 3] = excl + s2;
}

// ---- pass 2: per-bucket build of cnt/dinv/rowptr/csr ----
__global__ __launch_bounds__(256) void k_build(const unsigned int* __restrict__ staging,
                                               const int* __restrict__ gcur,
                                               const int* __restrict__ bbase,
                                               int* __restrict__ cntg,
                                               float* __restrict__ dinv,
                                               int* __restrict__ rowptr,
                                               int* __restrict__ csr) {
    __shared__ int lcnt[128];
    __shared__ int lscan[2][128];
    __shared__ int lcur[128];
    const int tid = threadIdx.x;
    const int b = blockIdx.x;
    const int tot = min(gcur[b], CAPB);
    const int bb = bbase[b];
    const unsigned int* st = staging + (size_t)b * CAPB;
    if (tid < 128) lcnt[tid] = 0;
    __syncthreads();
    for (int i = tid; i < tot; i += 256) {
        unsigned int v = st[i];
        atomicAdd(&lcnt[v >> 17], 1);
    }
    __syncthreads();
    int pi = 0;
    if (tid < 128) lscan[0][tid] = lcnt[tid];
    __syncthreads();
    for (int off = 1; off < 128; off <<= 1) {
        if (tid < 128) {
            int x = lscan[pi][tid];
            if (tid >= off) x += lscan[pi][tid - off];
            lscan[pi ^ 1][tid] = x;
        }
        __syncthreads();
        pi ^= 1;
    }
    if (tid < 128) {
        int c = lcnt[tid];
        int excl = lscan[pi][tid] - c;
        lcur[tid] = excl;
        int node = (b << BSH) + tid;
        if (node < NN) {
            cntg[node] = c;
            dinv[node] = rsqrtf((float)(c + 1));
            rowptr[node] = bb + excl;
        }
    }
    __syncthreads();
    for (int i = tid; i < tot; i += 256) {
        unsigned int v = st[i];
        int pos = atomicAdd(&lcur[v >> 17], 1);
        csr[bb + pos] = (int)(v & 0x1ffffu);
    }
}

// ---- fused weight prep: all three matrices, fragment-contiguous hi/lo bf16 ----
// Wt[((k>>5)*MP + m)*32 + (k&31)]
__global__ void k_wprep(const float* __restrict__ W1, unsigned short* __restrict__ W1h,
                        unsigned short* __restrict__ W1l,
                        const float* __restrict__ W2, unsigned short* __restrict__ W2h,
                        unsigned short* __restrict__ W2l,
                        const float* __restrict__ W3, unsigned short* __restrict__ W3h,
                        unsigned short* __restrict__ W3l) {
    int idx = blockIdx.x * blockDim.x + threadIdx.x;
    const float* W;
    unsigned short *Wh, *Wl;
    int K, M, MP;
    if (idx < 256 * 128) {
        W = W1; Wh = W1h; Wl = W1l; K = 128; M = 256; MP = 256;
    } else if (idx < 256 * 128 + 256 * 256) {
        idx -= 256 * 128;
        W = W2; Wh = W2h; Wl = W2l; K = 256; M = 256; MP = 256;
    } else if (idx < 256 * 128 + 256 * 256 + 64 * 256) {
        idx -= 256 * 128 + 256 * 256;
        W = W3; Wh = W3h; Wl = W3l; K = 256; M = 40; MP = 64;
    } else {
        return;
    }
    int m = idx / K, k = idx - m * K;
    float v = (m < M) ? W[(size_t)k * M + m] : 0.f;
    unsigned short h, l;
    f2bf2(v, h, l);
    size_t dst = ((size_t)(k >> 5) * MP + m) * 32 + (k & 31);
    Wh[dst] = h;
    Wl[dst] = l;
}

// ---- z * dinv -> signed int8, column-blocked [4][NN][32] + per-row scale ----
__global__ __launch_bounds__(256) void k_zpb8(const float* __restrict__ z,
                                              const float* __restrict__ dinv,
                                              unsigned char* __restrict__ zp8,
                                              float* __restrict__ scaleZ) {
    int wv = (blockIdx.x * blockDim.x + threadIdx.x) >> 6;
    int lane = threadIdx.x & 63;
    if (wv >= NN) return;
    float2 v = *(const float2*)(z + (size_t)wv * FIN + lane * 2);
    float d = dinv[wv];
    float a0 = v.x * d, a1 = v.y * d;
    float m = fmaxf(fabsf(a0), fabsf(a1));
#pragma unroll
    for (int off = 1; off < 64; off <<= 1) m = fmaxf(m, __shfl_xor(m, off));
    float inv = m > 0.f ? 127.f / m : 0.f;
    int q0 = (int)rintf(a0 * inv), q1 = (int)rintf(a1 * inv);
    unsigned short pk = (unsigned short)((q0 & 0xff) | ((q1 & 0xff) << 8));
    // features 2*lane, 2*lane+1 -> slice lane>>4, inner (2*lane)&31
    *(unsigned short*)(zp8 + (size_t)(lane >> 4) * ((size_t)NN * 32) +
                       (size_t)wv * 32 + ((lane * 2) & 31)) = pk;
    if (lane == 0) scaleZ[wv] = m * (1.f / 127.f);
}

// ---- BN+ReLU+dinv -> unsigned int8, column-blocked [4][NN][64] + scale ----
__global__ __launch_bounds__(256) void k_bnr8(const unsigned short* __restrict__ x,
                                              const float* __restrict__ scale,
                                              const float* __restrict__ shift,
                                              const float* __restrict__ dinv,
                                              unsigned char* __restrict__ y8,
                                              float* __restrict__ scaleY) {
    int wv = (blockIdx.x * blockDim.x + threadIdx.x) >> 6;
    int lane = threadIdx.x & 63;
    if (wv >= NN) return;
    uint2 u = *(const uint2*)(x + (size_t)wv * 256 + lane * 4);
    float4 sc = *(const float4*)(scale + lane * 4);
    float4 sh = *(const float4*)(shift + lane * 4);
    float d = dinv[wv];
    float v0 = fmaxf(__uint_as_float(u.x << 16) * sc.x + sh.x, 0.f) * d;
    float v1 = fmaxf(__uint_as_float(u.x & 0xffff0000u) * sc.y + sh.y, 0.f) * d;
    float v2 = fmaxf(__uint_as_float(u.y << 16) * sc.z + sh.z, 0.f) * d;
    float v3 = fmaxf(__uint_as_float(u.y & 0xffff0000u) * sc.w + sh.w, 0.f) * d;
    float m = fmaxf(fmaxf(v0, v1), fmaxf(v2, v3));
#pragma unroll
    for (int off = 1; off < 64; off <<= 1) m = fmaxf(m, __shfl_xor(m, off));
    float inv = m > 0.f ? 255.f / m : 0.f;
    unsigned int q0 = (unsigned int)(v0 * inv + 0.5f);
    unsigned int q1 = (unsigned int)(v1 * inv + 0.5f);
    unsigned int q2 = (unsigned int)(v2 * inv + 0.5f);
    unsigned int q3 = (unsigned int)(v3 * inv + 0.5f);
    // features 4*lane..4*lane+3 -> slice lane>>4, inner (4*lane)&63
    *(unsigned int*)(y8 + (size_t)(lane >> 4) * ((size_t)NN * 64) +
                     (size_t)wv * 64 + ((lane * 4) & 63)) =
        q0 | (q1 << 8) | (q2 << 16) | (q3 << 24);
    if (lane == 0) scaleY[wv] = m * (1.f / 255.f);
}

// ---- XCD-sharded int8 gather: slice = blockIdx%NSL, 8 edges per VMEM instr ----
// Table layout [NSL][NN][SW]. 8 lanes per edge (PB=SW/8 bytes/lane); edge
// indices+scales in SGPRs (scalar CSR walk), fanned out by cndmask tree on
// g=lane>>3. Virtual edge 0 = self; tail masked with scale 0. 2-stage load
// rotation. Cross-group reduce: shfl_xor 8/16/32. oa stays [row][F] bf16.
template <int F, int SW, bool SIGNED>
__global__ __launch_bounds__(256) void k_aggs(const unsigned char* __restrict__ tab,
                                              const float* __restrict__ rscale,
                                              const float* __restrict__ dinv,
                                              const int* __restrict__ rowptr,
                                              const int* __restrict__ cnt,
                                              const int* __restrict__ csr,
                                              unsigned short* __restrict__ oa) {
    constexpr int NSL = F / SW;
    constexpr int PB = SW / 8;
    const int slice = blockIdx.x % NSL;
    const int sb = blockIdx.x / NSL;
    const int nsb = gridDim.x / NSL;
    const int wid = threadIdx.x >> 6;
    const int lane = threadIdx.x & 63;
    const int g = lane >> 3;
    const int fb = (lane & 7) * PB;
    const unsigned char* tsl = tab + (size_t)slice * ((size_t)NN * SW);

    for (int row0 = sb * 4 + wid; row0 < NN; row0 += nsb * 4) {
        const int row = __builtin_amdgcn_readfirstlane(row0);
        const int rp = __builtin_amdgcn_readfirstlane(rowptr[row]);
        const int cn = __builtin_amdgcn_readfirstlane(cnt[row]);
        float acc[PB];
#pragma unroll
        for (int k = 0; k < PB; k++) acc[k] = 0.f;

        auto loadsel = [&](int b, int& sel, float& se) {
            int ic[8];
            float sc[8];
            const int e0 = b * 8;
#pragma unroll
            for (int j = 0; j < 8; j++) {
                int e = e0 + j;
                int idx = (e == 0 || e > cn) ? row : csr[rp + e - 1];
                ic[j] = idx;
                sc[j] = (e > cn) ? 0.f : rscale[idx];
            }
            int s01 = (g & 1) ? ic[1] : ic[0], s23 = (g & 1) ? ic[3] : ic[2];
            int s45 = (g & 1) ? ic[5] : ic[4], s67 = (g & 1) ? ic[7] : ic[6];
            int t0 = (g & 2) ? s23 : s01, t1 = (g & 2) ? s67 : s45;
            sel = (g & 4) ? t1 : t0;
            float w01 = (g & 1) ? sc[1] : sc[0], w23 = (g & 1) ? sc[3] : sc[2];
            float w45 = (g & 1) ? sc[5] : sc[4], w67 = (g & 1) ? sc[7] : sc[6];
            float u0 = (g & 2) ? w23 : w01, u1 = (g & 2) ? w67 : w45;
            se = (g & 4) ? u1 : u0;
        };
        auto payload = [&](int sel) {
            uint2 u;
            if constexpr (PB == 4) {
                u.x = *(const unsigned int*)(tsl + (size_t)sel * SW + fb);
                u.y = 0u;
            } else {
                u = *(const uint2*)(tsl + (size_t)sel * SW + fb);
            }
            return u;
        };
        auto consume = [&](uint2 u, float se) {
            acc[0] += se * (SIGNED ? sbyte(u.x, 0) : ub(u.x, 0));
            acc[1] += se * (SIGNED ? sbyte(u.x, 1) : ub(u.x, 1));
            acc[2] += se * (SIGNED ? sbyte(u.x, 2) : ub(u.x, 2));
            acc[3] += se * (SIGNED ? sbyte(u.x, 3) : ub(u.x, 3));
            if constexpr (PB == 8) {
                acc[4] += se * (SIGNED ? sbyte(u.y, 0) : ub(u.y, 0));
                acc[5] += se * (SIGNED ? sbyte(u.y, 1) : ub(u.y, 1));
                acc[6] += se * (SIGNED ? sbyte(u.y, 2) : ub(u.y, 2));
                acc[7] += se * (SIGNED ? sbyte(u.y, 3) : ub(u.y, 3));
            }
        };

        const int nbat = (cn + 8) >> 3;
        int selc;
        float sec;
        loadsel(0, selc, sec);
        uint2 uc = payload(selc);
        for (int b = 1; b < nbat; b++) {
            int seln;
            float sen;
            loadsel(b, seln, sen);
            uint2 un = payload(seln);
            consume(uc, sec);
            uc = un;
            sec = sen;
        }
        consume(uc, sec);

#pragma unroll
        for (int k = 0; k < PB; k++) {
            acc[k] += __shfl_xor(acc[k], 8);
            acc[k] += __shfl_xor(acc[k], 16);
            acc[k] += __shfl_xor(acc[k], 32);
        }
        const float d = dinv[row];
        if (lane < 8) {
            unsigned short* dst = oa + (size_t)row * F + slice * SW + lane * PB;
            if constexpr (PB == 4) {
                uint2 o;
                o.x = (unsigned int)f2bf(acc[0] * d) | ((unsigned int)f2bf(acc[1] * d) << 16);
                o.y = (unsigned int)f2bf(acc[2] * d) | ((unsigned int)f2bf(acc[3] * d) << 16);
                *(uint2*)dst = o;
            } else {
                uint4 o;
                o.x = (unsigned int)f2bf(acc[0] * d) | ((unsigned int)f2bf(acc[1] * d) << 16);
                o.y = (unsigned int)f2bf(acc[2] * d) | ((unsigned int)f2bf(acc[3] * d) << 16);
                o.z = (unsigned int)f2bf(acc[4] * d) | ((unsigned int)f2bf(acc[5] * d) << 16);
                o.w = (unsigned int)f2bf(acc[6] * d) | ((unsigned int)f2bf(acc[7] * d) << 16);
                *(uint4*)dst = o;
            }
        }
    }
}

// ---- GEMM: 64-row x 128-col tile; A bf16, W hi/lo; bias + BN stats fused ----
template <int K>
__global__ __launch_bounds__(256) void k_gemm(const unsigned short* __restrict__ A,
                                              const unsigned short* __restrict__ Wth,
                                              const unsigned short* __restrict__ Wtl,
                                              const float* __restrict__ bias,
                                              unsigned short* __restrict__ outX,
                                              float* __restrict__ s1,
                                              float* __restrict__ s2) {
    __shared__ unsigned short sA[64][40];
    const int t = threadIdx.x;
    const int w = t >> 6, lane = t & 63;
    const int quad = lane >> 4, l16 = lane & 15;
    const int rowBase = blockIdx.y * 64;
    const int colW = blockIdx.x * 128 + w * 32;
    f32x4 acc[4][2];
#pragma unroll
    for (int i = 0; i < 4; i++)
#pragma unroll
        for (int j = 0; j < 2; j++) acc[i][j] = (f32x4)0.f;

    for (int k0 = 0; k0 < K; k0 += 32) {
        int gr = rowBase + (t >> 2);
        int4 v = {0, 0, 0, 0};
        if (gr < NN) v = *(const int4*)(A + (size_t)gr * K + k0 + (t & 3) * 8);
        __syncthreads();
        *(int4*)&sA[t >> 2][(t & 3) * 8] = v;
        __syncthreads();
        const int kb = k0 >> 5;
        bf8 bh[2], bl[2];
#pragma unroll
        for (int j = 0; j < 2; j++) {
            size_t bo = ((size_t)(kb * 256 + colW + j * 16 + l16)) * 32 + quad * 8;
            bh[j] = *(const bf8*)(Wth + bo);
            bl[j] = *(const bf8*)(Wtl + bo);
        }
#pragma unroll
        for (int i = 0; i < 4; i++) {
            bf8 a = *(const bf8*)&sA[i * 16 + l16][quad * 8];
#pragma unroll
            for (int j = 0; j < 2; j++) {
                acc[i][j] = __builtin_amdgcn_mfma_f32_16x16x32_bf16(a, bh[j], acc[i][j], 0, 0, 0);
                acc[i][j] = __builtin_amdgcn_mfma_f32_16x16x32_bf16(a, bl[j], acc[i][j], 0, 0, 0);
            }
        }
    }
#pragma unroll
    for (int j = 0; j < 2; j++) {
        int col = colW + j * 16 + l16;
        float b = bias[col];
        float s1p = 0.f, s2p = 0.f;
#pragma unroll
        for (int i = 0; i < 4; i++) {
#pragma unroll
            for (int r = 0; r < 4; r++) {
                int row = rowBase + i * 16 + quad * 4 + r;
                if (row < NN) {
                    float v = acc[i][j][r] + b;
                    s1p += v;
                    s2p += v * v;
                    outX[(size_t)row * 256 + col] = f2bf(v);
                }
            }
        }
        s1p += __shfl_xor(s1p, 16); s1p += __shfl_xor(s1p, 32);
        s2p += __shfl_xor(s2p, 16); s2p += __shfl_xor(s2p, 32);
        if (quad == 0) {
            atomicAdd(&s1[col], s1p);
            atomicAdd(&s2[col], s2p);
        }
    }
}

// ---- layer-3 GEMM -> signed int8 H3, column-blocked [2][NN][32] + scale ----
__global__ __launch_bounds__(256) void k_mgemm3(const unsigned short* __restrict__ y2,
                                                const unsigned short* __restrict__ Wth,
                                                const unsigned short* __restrict__ Wtl,
                                                unsigned char* __restrict__ H8,
                                                float* __restrict__ scaleH) {
    __shared__ unsigned short sA[128][40];
    __shared__ float sM[128][4];
    const int t = threadIdx.x;
    const int w = t >> 6, lane = t & 63;
    const int quad = lane >> 4, l16 = lane & 15;
    const int rowBase = blockIdx.x << 7;
    f32x4 acc[8];
#pragma unroll
    for (int i = 0; i < 8; i++) acc[i] = (f32x4)0.f;

    for (int k0 = 0; k0 < 256; k0 += 32) {
        const int kb = k0 >> 5;
        int id0 = t, id1 = t + 256;
        int gr0 = rowBase + (id0 >> 2), gr1 = rowBase + (id1 >> 2);
        int4 zz = {0, 0, 0, 0};
        int4 v0 = (gr0 < NN) ? *(const int4*)(y2 + (size_t)gr0 * 256 + k0 + (id0 & 3) * 8) : zz;
        int4 v1 = (gr1 < NN) ? *(const int4*)(y2 + (size_t)gr1 * 256 + k0 + (id1 & 3) * 8) : zz;
        __syncthreads();
        *(int4*)&sA[id0 >> 2][(id0 & 3) * 8] = v0;
        *(int4*)&sA[id1 >> 2][(id1 & 3) * 8] = v1;
        __syncthreads();
        size_t bo = ((size_t)(kb * 64 + w * 16 + l16)) * 32 + quad * 8;
        bf8 bh = *(const bf8*)(Wth + bo);
        bf8 bl = *(const bf8*)(Wtl + bo);
#pragma unroll
        for (int i = 0; i < 8; i++) {
            bf8 a = *(const bf8*)&sA[i * 16 + l16][quad * 8];
            acc[i] = __builtin_amdgcn_mfma_f32_16x16x32_bf16(a, bh, acc[i], 0, 0, 0);
            acc[i] = __builtin_amdgcn_mfma_f32_16x16x32_bf16(a, bl, acc[i], 0, 0, 0);
        }
    }
#pragma unroll
    for (int i = 0; i < 8; i++) {
#pragma unroll
        for (int r = 0; r < 4; r++) {
            float m = fabsf(acc[i][r]);
            m = fmaxf(m, __shfl_xor(m, 1));
            m = fmaxf(m, __shfl_xor(m, 2));
            m = fmaxf(m, __shfl_xor(m, 4));
            m = fmaxf(m, __shfl_xor(m, 8));
            if (l16 == 0) sM[i * 16 + quad * 4 + r][w] = m;
        }
    }
    __syncthreads();
    const int col = w * 16 + l16;
#pragma unroll
    for (int i = 0; i < 8; i++) {
#pragma unroll
        for (int r = 0; r < 4; r++) {
            int rloc = i * 16 + quad * 4 + r;
            int row = rowBase + rloc;
            float m = fmaxf(fmaxf(sM[rloc][0], sM[rloc][1]), fmaxf(sM[rloc][2], sM[rloc][3]));
            float inv = m > 0.f ? 127.f / m : 0.f;
            if (row < NN) {
                int q = (int)rintf(acc[i][r] * inv);
                H8[(size_t)(col >> 5) * ((size_t)NN * 32) + (size_t)row * 32 + (col & 31)] =
                    (unsigned char)(q & 0xff);
                if (w == 0 && l16 == 0) scaleH[row] = m * (1.f / 127.f);
            }
        }
    }
}

// ---- final XCD-sharded aggregation from H8 [2][NN][32] -> f32 out + bias ----
__global__ __launch_bounds__(256) void k_aggsfb(const unsigned char* __restrict__ tab,
                                                const float* __restrict__ rscale,
                                                const float* __restrict__ dinv,
                                                const int* __restrict__ rowptr,
                                                const int* __restrict__ cnt,
                                                const int* __restrict__ csr,
                                                const float* __restrict__ bias,
                                                float* __restrict__ out) {
    constexpr int SW = 32;
    constexpr int NSL = 2;
    const int slice = blockIdx.x % NSL;
    const int sb = blockIdx.x / NSL;
    const int nsb = gridDim.x / NSL;
    const int wid = threadIdx.x >> 6;
    const int lane = threadIdx.x & 63;
    const int g = lane >> 3;
    const int fb = (lane & 7) * 4;
    const unsigned char* tsl = tab + (size_t)slice * ((size_t)NN * SW);

    for (int row0 = sb * 4 + wid; row0 < NN; row0 += nsb * 4) {
        const int row = __builtin_amdgcn_readfirstlane(row0);
        const int rp = __builtin_amdgcn_readfirstlane(rowptr[row]);
        const int cn = __builtin_amdgcn_readfirstlane(cnt[row]);
        float a0 = 0.f, a1 = 0.f, a2 = 0.f, a3 = 0.f;

        auto loadsel = [&](int b, int& sel, float& se) {
            int ic[8];
            float sc[8];
            const int e0 = b * 8;
#pragma unroll
            for (int j = 0; j < 8; j++) {
                int e = e0 + j;
                int idx = (e == 0 || e > cn) ? row : csr[rp + e - 1];
                ic[j] = idx;
                sc[j] = (e > cn) ? 0.f : rscale[idx];
            }
            int s01 = (g & 1) ? ic[1] : ic[0], s23 = (g & 1) ? ic[3] : ic[2];
            int s45 = (g & 1) ? ic[5] : ic[4], s67 = (g & 1) ? ic[7] : ic[6];
            int t0 = (g & 2) ? s23 : s01, t1 = (g & 2) ? s67 : s45;
            sel = (g & 4) ? t1 : t0;
            float w01 = (g & 1) ? sc[1] : sc[0], w23 = (g & 1) ? sc[3] : sc[2];
            float w45 = (g & 1) ? sc[5] : sc[4], w67 = (g & 1) ? sc[7] : sc[6];
            float u0 = (g & 2) ? w23 : w01, u1 = (g & 2) ? w67 : w45;
            se = (g & 4) ? u1 : u0;
        };

        const int nbat = (cn + 8) >> 3;
        int selc;
        float sec;
        loadsel(0, selc, sec);
        unsigned int uc = *(const unsigned int*)(tsl + (size_t)selc * SW + fb);
        for (int b = 1; b < nbat; b++) {
            int seln;
            float sen;
            loadsel(b, seln, sen);
            unsigned int un = *(const unsigned int*)(tsl + (size_t)seln * SW + fb);
            a0 += sec * sbyte(uc, 0); a1 += sec * sbyte(uc, 1);
            a2 += sec * sbyte(uc, 2); a3 += sec * sbyte(uc, 3);
            uc = un;
            sec = sen;
        }
        a0 += sec * sbyte(uc, 0); a1 += sec * sbyte(uc, 1);
        a2 += sec * sbyte(uc, 2); a3 += sec * sbyte(uc, 3);

        a0 += __shfl_xor(a0, 8); a0 += __shfl_xor(a0, 16); a0 += __shfl_xor(a0, 32);
        a1 += __shfl_xor(a1, 8); a1 += __shfl_xor(a1, 16); a1 += __shfl_xor(a1, 32);
        a2 += __shfl_xor(a2, 8); a2 += __shfl_xor(a2, 16); a2 += __shfl_xor(a2, 32);
        a3 += __shfl_xor(a3, 8); a3 += __shfl_xor(a3, 16); a3 += __shfl_xor(a3, 32);

        const float d = dinv[row];
        const int f0 = slice * SW + fb;
        if (lane < 8 && f0 < FOUT) {
            float4 o;
            o.x = a0 * d + bias[f0 + 0];
            o.y = a1 * d + bias[f0 + 1];
            o.z = a2 * d + bias[f0 + 2];
            o.w = a3 * d + bias[f0 + 3];
            *(float4*)(out + (size_t)row * FOUT + f0) = o;
        }
    }
}

__global__ void k_bnfold(const float* __restrict__ s1, const float* __restrict__ s2,
                         const float* __restrict__ g, const float* __restrict__ be,
                         float* __restrict__ scale, float* __restrict__ shift) {
    int c = threadIdx.x;
    if (c < 256) {
        float mean = s1[c] * (1.f / NN);
        float var = s2[c] * (1.f / NN) - mean * mean;
        float sc = g[c] * rsqrtf(var + EPSV);
        scale[c] = sc;
        shift[c] = be[c] - mean * sc;
    }
}

// ---- BN+ReLU bf16->bf16 table (x dinv) — layer-2 output for mgemm3 ----
__global__ void k_bnr(const unsigned short* __restrict__ x,
                      const float* __restrict__ scale, const float* __restrict__ shift,
                      const float* __restrict__ dinv, unsigned short* __restrict__ oy) {
    int i = blockIdx.x * blockDim.x + threadIdx.x;
    if (i >= NN * 128) return;
    int row = i >> 7;
    int c = (i & 127) * 2;
    unsigned int u = ((const unsigned int*)x)[i];
    float x0 = __uint_as_float(u << 16);
    float x1 = __uint_as_float(u & 0xffff0000u);
    float d = dinv[row];
    float v0 = fmaxf(x0 * scale[c + 0] + shift[c + 0], 0.f) * d;
    float v1 = fmaxf(x1 * scale[c + 1] + shift[c + 1], 0.f) * d;
    ((unsigned int*)oy)[i] = (unsigned int)f2bf(v0) | ((unsigned int)f2bf(v1) << 16);
}

extern "C" void kernel_launch(void* const* d_in, const int* in_sizes, int n_in,
                              void* d_out, int out_size, void* d_ws, size_t ws_size,
                              hipStream_t stream) {
    const int* ei = (const int*)d_in[0];
    const float* z = (const float*)d_in[1];
    const float* W1 = (const float*)d_in[2];
    const float* b1 = (const float*)d_in[3];
    const float* g1 = (const float*)d_in[4];
    const float* be1 = (const float*)d_in[5];
    const float* W2 = (const float*)d_in[6];
    const float* b2 = (const float*)d_in[7];
    const float* g2 = (const float*)d_in[8];
    const float* be2 = (const float*)d_in[9];
    const float* W3 = (const float*)d_in[10];
    const float* b3 = (const float*)d_in[11];
    float* out = (float*)d_out;

    char* w = (char*)d_ws;
    size_t o = 0;
    auto take = [&](size_t bytes) {
        char* p = w + o;
        o = (o + bytes + 255) & ~(size_t)255;
        return p;
    };
    int* cnt = (int*)take((size_t)NN * 4);
    int* rowptr = (int*)take((size_t)NN * 4);
    int* gcur = (int*)take(NBKT * 4);
    int* bbase = (int*)take(NBKT * 4);
    int* csr = (int*)take((size_t)NE * 4 + 256);
    unsigned int* staging = (unsigned int*)take((size_t)NBKT * CAPB * 4);
    float* dinv = (float*)take((size_t)NN * 4);
    float* stat = (float*)take(4 * 256 * 4);
    float* sc1 = (float*)take(256 * 4);
    float* sh1 = (float*)take(256 * 4);
    float* sc2 = (float*)take(256 * 4);
    float* sh2 = (float*)take(256 * 4);
    unsigned short* Wt1h = (unsigned short*)take(256 * 128 * 2);
    unsigned short* Wt1l = (unsigned short*)take(256 * 128 * 2);
    unsigned short* Wt2h = (unsigned short*)take(256 * 256 * 2);
    unsigned short* Wt2l = (unsigned short*)take(256 * 256 * 2);
    unsigned short* Wt3h = (unsigned short*)take(64 * 256 * 2);
    unsigned short* Wt3l = (unsigned short*)take(64 * 256 * 2);
    unsigned char* zp8 = (unsigned char*)take((size_t)NN * FIN);
    unsigned char* y1_8 = (unsigned char*)take((size_t)NN * FH);
    unsigned char* H8 = (unsigned char*)take((size_t)NN * 64);
    float* scaleZ = (float*)take((size_t)NN * 4);
    float* scaleY = (float*)take((size_t)NN * 4);
    float* scaleH = (float*)take((size_t)NN * 4);
    unsigned short* P1 = (unsigned short*)take((size_t)NN * 256 * 2);
    unsigned short* P2 = (unsigned short*)take((size_t)NN * 512 * 2);

    unsigned short* a1 = P1;
    unsigned short* x1 = P2;
    unsigned short* a2 = P2 + (size_t)NN * 256;
    unsigned short* x2 = P1;
    unsigned short* y2 = P2;
    float* s1a = stat, *s2a = stat + 256, *s1b = stat + 512, *s2b = stat + 768;

    hipMemsetAsync(gcur, 0, NBKT * 4, stream);
    hipMemsetAsync(stat, 0, 4 * 256 * 4, stream);

    // CSR build (two-level counting sort; dtype flag computed inline)
    k_bin<<<(NE + CHNK - 1) / CHNK, 256, 0, stream>>>(ei, gcur, staging);
    k_bucketscan<<<1, 256, 0, stream>>>(gcur, bbase);
    k_build<<<NBKT, 256, 0, stream>>>(staging, gcur, bbase, cnt, dinv, rowptr, csr);

    k_wprep<<<(256 * 128 + 256 * 256 + 64 * 256 + 255) / 256, 256, 0, stream>>>(
        W1, Wt1h, Wt1l, W2, Wt2h, Wt2l, W3, Wt3h, Wt3l);

    const int GR = (NN + 63) / 64;
    const int WV = (NN + 3) / 4;

    // layer 1
    k_zpb8<<<WV, 256, 0, stream>>>(z, dinv, zp8, scaleZ);
    k_aggs<128, 32, true><<<2560, 256, 0, stream>>>(zp8, scaleZ, dinv, rowptr, cnt, csr, a1);
    k_gemm<128><<<dim3(2, GR), 256, 0, stream>>>(a1, Wt1h, Wt1l, b1, x1, s1a, s2a);
    k_bnfold<<<1, 256, 0, stream>>>(s1a, s2a, g1, be1, sc1, sh1);
    k_bnr8<<<WV, 256, 0, stream>>>(x1, sc1, sh1, dinv, y1_8, scaleY);

    // layer 2
    k_aggs<256, 64, false><<<2560, 256, 0, stream>>>(y1_8, scaleY, dinv, rowptr, cnt, csr, a2);
    k_gemm<256><<<dim3(2, GR), 256, 0, stream>>>(a2, Wt2h, Wt2l, b2, x2, s1b, s2b);
    k_bnfold<<<1, 256, 0, stream>>>(s1b, s2b, g2, be2, sc2, sh2);
    k_bnr<<<(NN * 128 + 255) / 256, 256, 0, stream>>>(x2, sc2, sh2, dinv, y2);

    // layer 3
    k_mgemm3<<<NBKT, 256, 0, stream>>>(y2, Wt3h, Wt3l, H8, scaleH);
    k_aggsfb<<<2560, 256, 0, stream>>>(H8, scaleH, dinv, rowptr, cnt, csr, b3, out);
}

// Round 5
// 1163.020 us; speedup vs baseline: 1.7519x; 1.7519x over previous
//
#include <hip/hip_runtime.h>

// GCN 3-layer: N=100000, E=3200000, 128 -> 256 -> 256 -> 40
// Round 12: multi-edge payload instructions WITHOUT shfl/LDS (r2's confound)
// and WITHOUT sharding (r4's confound). Scalar CSR walk (SGPR idx/scale);
// per-lane payload address = cndmask-tree select of SGPR row offsets:
//   agg256: 16 lanes/edge x 16B -> 4 edges per dwordx4 instr
//   agg128:  8 lanes/edge x 16B -> 8 edges per instr
//   aggfb :  8 lanes/edge x  8B -> 8 edges per instr
// Self = virtual edge 0; tail edges masked with scale 0. One xor-reduce/row.
// Attacks the per-CU VMEM-instruction slot cap (r1-r4 bracketed: not VALU,
// not bytes/lines, not per-wave depth, not L2 footprint).

#define NN   100000
#define NE   3200000
#define FIN  128
#define FH   256
#define FOUT 40
#define EPSV 1e-5f

#define BSH   7
#define NBKT  ((NN + 127) >> BSH)  // 782
#define CAPB  8192
#define CHNK  4096

typedef __attribute__((ext_vector_type(8))) short bf8;
typedef __attribute__((ext_vector_type(4))) float f32x4;

__device__ __forceinline__ unsigned short f2bf(float x) {
    unsigned int u = __float_as_uint(x);
    unsigned int r = u + 0x7fffu + ((u >> 16) & 1u);
    return (unsigned short)(r >> 16);
}
__device__ __forceinline__ float bf2f(unsigned short h) {
    return __uint_as_float(((unsigned int)h) << 16);
}
__device__ __forceinline__ void f2bf2(float x, unsigned short& hi, unsigned short& lo) {
    unsigned short h = f2bf(x);
    hi = h;
    lo = f2bf(x - bf2f(h));
}
__device__ __forceinline__ float ub(unsigned int u, int k) {
    return (float)((u >> (8 * k)) & 0xffu);
}
__device__ __forceinline__ float sbyte(unsigned int u, int k) {
    return (float)(int)(signed char)((u >> (8 * k)) & 0xffu);
}

// ---- pass 1: bin edges by dst>>7 into fixed-slot staging (flag computed inline) ----
__global__ __launch_bounds__(256) void k_bin(const int* __restrict__ ei,
                                             int* __restrict__ gcur,
                                             unsigned int* __restrict__ staging) {
    __shared__ int hcnt[NBKT];
    __shared__ int hbase[NBKT];
    __shared__ int sflag;
    const int tid = threadIdx.x;
    const int e0 = blockIdx.x * CHNK;
    for (int b = tid; b < NBKT; b += 256) hcnt[b] = 0;
    if (tid == 0) {
        int zz = 0;
        for (int i = 0; i < 64; i++) zz |= ei[2 * i + 1];
        sflag = (zz == 0) ? 1 : 0;
    }
    __syncthreads();
    const int f = sflag;
    for (int r = 0; r < CHNK / 256; r++) {
        int e = e0 + r * 256 + tid;
        if (e < NE) {
            int d = f ? ei[2 * (NE + e)] : ei[NE + e];
            atomicAdd(&hcnt[d >> BSH], 1);
        }
    }
    __syncthreads();
    for (int b = tid; b < NBKT; b += 256) {
        int c = hcnt[b];
        hbase[b] = c ? atomicAdd(&gcur[b], c) : 0;
    }
    __syncthreads();
    for (int b = tid; b < NBKT; b += 256) hcnt[b] = 0;
    __syncthreads();
    for (int r = 0; r < CHNK / 256; r++) {
        int e = e0 + r * 256 + tid;
        if (e < NE) {
            int s = f ? ei[2 * e] : ei[e];
            int d = f ? ei[2 * (NE + e)] : ei[NE + e];
            int b = d >> BSH;
            int loc = atomicAdd(&hcnt[b], 1);
            int pos = hbase[b] + loc;
            if (pos < CAPB)
                staging[(size_t)b * CAPB + pos] =
                    (unsigned int)s | ((unsigned int)(d & 127) << 17);
        }
    }
}

__global__ void k_bucketscan(const int* __restrict__ gcur, int* __restrict__ bbase) {
    __shared__ int sb2[2][256];
    int t = threadIdx.x;
    int base = t * 4;
    int v0 = (base + 0 < NBKT) ? gcur[base + 0] : 0;
    int v1 = (base + 1 < NBKT) ? gcur[base + 1] : 0;
    int v2 = (base + 2 < NBKT) ? gcur[base + 2] : 0;
    int v3 = (base + 3 < NBKT) ? gcur[base + 3] : 0;
    int s0 = v0, s1 = s0 + v1, s2 = s1 + v2, s3 = s2 + v3;
    sb2[0][t] = s3;
    __syncthreads();
    int pi = 0;
    for (int off = 1; off < 256; off <<= 1) {
        int x = sb2[pi][t];
        if (t >= off) x += sb2[pi][t - off];
        sb2[pi ^ 1][t] = x;
        __syncthreads();
        pi ^= 1;
    }
    int excl = sb2[pi][t] - s3;
    if (base + 0 < NBKT) bbase[base + 0] = excl;
    if (base + 1 < NBKT) bbase[base + 1] = excl + s0;
    if (base + 2 < NBKT) bbase[base + 2] = excl + s1;
    if (base + 3 < NBKT) bbase[base + 3] = excl + s2;
}

// ---- pass 2: per-bucket build of cnt/dinv/rowptr/csr ----
__global__ __launch_bounds__(256) void k_build(const unsigned int* __restrict__ staging,
                                               const int* __restrict__ gcur,
                                               const int* __restrict__ bbase,
                                               int* __restrict__ cntg,
                                               float* __restrict__ dinv,
                                               int* __restrict__ rowptr,
                                               int* __restrict__ csr) {
    __shared__ int lcnt[128];
    __shared__ int lscan[2][128];
    __shared__ int lcur[128];
    const int tid = threadIdx.x;
    const int b = blockIdx.x;
    const int tot = min(gcur[b], CAPB);
    const int bb = bbase[b];
    const unsigned int* st = staging + (size_t)b * CAPB;
    if (tid < 128) lcnt[tid] = 0;
    __syncthreads();
    for (int i = tid; i < tot; i += 256) {
        unsigned int v = st[i];
        atomicAdd(&lcnt[v >> 17], 1);
    }
    __syncthreads();
    int pi = 0;
    if (tid < 128) lscan[0][tid] = lcnt[tid];
    __syncthreads();
    for (int off = 1; off < 128; off <<= 1) {
        if (tid < 128) {
            int x = lscan[pi][tid];
            if (tid >= off) x += lscan[pi][tid - off];
            lscan[pi ^ 1][tid] = x;
        }
        __syncthreads();
        pi ^= 1;
    }
    if (tid < 128) {
        int c = lcnt[tid];
        int excl = lscan[pi][tid] - c;
        lcur[tid] = excl;
        int node = (b << BSH) + tid;
        if (node < NN) {
            cntg[node] = c;
            dinv[node] = rsqrtf((float)(c + 1));
            rowptr[node] = bb + excl;
        }
    }
    __syncthreads();
    for (int i = tid; i < tot; i += 256) {
        unsigned int v = st[i];
        int pos = atomicAdd(&lcur[v >> 17], 1);
        csr[bb + pos] = (int)(v & 0x1ffffu);
    }
}

// ---- fused weight prep: all three matrices, fragment-contiguous hi/lo bf16 ----
// Wt[((k>>5)*MP + m)*32 + (k&31)]
__global__ void k_wprep(const float* __restrict__ W1, unsigned short* __restrict__ W1h,
                        unsigned short* __restrict__ W1l,
                        const float* __restrict__ W2, unsigned short* __restrict__ W2h,
                        unsigned short* __restrict__ W2l,
                        const float* __restrict__ W3, unsigned short* __restrict__ W3h,
                        unsigned short* __restrict__ W3l) {
    int idx = blockIdx.x * blockDim.x + threadIdx.x;
    const float* W;
    unsigned short *Wh, *Wl;
    int K, M, MP;
    if (idx < 256 * 128) {
        W = W1; Wh = W1h; Wl = W1l; K = 128; M = 256; MP = 256;
    } else if (idx < 256 * 128 + 256 * 256) {
        idx -= 256 * 128;
        W = W2; Wh = W2h; Wl = W2l; K = 256; M = 256; MP = 256;
    } else if (idx < 256 * 128 + 256 * 256 + 64 * 256) {
        idx -= 256 * 128 + 256 * 256;
        W = W3; Wh = W3h; Wl = W3l; K = 256; M = 40; MP = 64;
    } else {
        return;
    }
    int m = idx / K, k = idx - m * K;
    float v = (m < M) ? W[(size_t)k * M + m] : 0.f;
    unsigned short h, l;
    f2bf2(v, h, l);
    size_t dst = ((size_t)(k >> 5) * MP + m) * 32 + (k & 31);
    Wh[dst] = h;
    Wl[dst] = l;
}

// ---- z * dinv -> signed int8 rows + per-row scale (wave per row) ----
__global__ __launch_bounds__(256) void k_zpb8(const float* __restrict__ z,
                                              const float* __restrict__ dinv,
                                              unsigned char* __restrict__ zp8,
                                              float* __restrict__ scaleZ) {
    int wv = (blockIdx.x * blockDim.x + threadIdx.x) >> 6;
    int lane = threadIdx.x & 63;
    if (wv >= NN) return;
    float2 v = *(const float2*)(z + (size_t)wv * FIN + lane * 2);
    float d = dinv[wv];
    float a0 = v.x * d, a1 = v.y * d;
    float m = fmaxf(fabsf(a0), fabsf(a1));
#pragma unroll
    for (int off = 1; off < 64; off <<= 1) m = fmaxf(m, __shfl_xor(m, off));
    float inv = m > 0.f ? 127.f / m : 0.f;
    int q0 = (int)rintf(a0 * inv), q1 = (int)rintf(a1 * inv);
    unsigned short pk = (unsigned short)((q0 & 0xff) | ((q1 & 0xff) << 8));
    *(unsigned short*)(zp8 + (size_t)wv * FIN + lane * 2) = pk;
    if (lane == 0) scaleZ[wv] = m * (1.f / 127.f);
}

// ---- BN+ReLU+dinv -> unsigned int8 rows + per-row scale (wave per row) ----
__global__ __launch_bounds__(256) void k_bnr8(const unsigned short* __restrict__ x,
                                              const float* __restrict__ scale,
                                              const float* __restrict__ shift,
                                              const float* __restrict__ dinv,
                                              unsigned char* __restrict__ y8,
                                              float* __restrict__ scaleY) {
    int wv = (blockIdx.x * blockDim.x + threadIdx.x) >> 6;
    int lane = threadIdx.x & 63;
    if (wv >= NN) return;
    uint2 u = *(const uint2*)(x + (size_t)wv * 256 + lane * 4);
    float4 sc = *(const float4*)(scale + lane * 4);
    float4 sh = *(const float4*)(shift + lane * 4);
    float d = dinv[wv];
    float v0 = fmaxf(__uint_as_float(u.x << 16) * sc.x + sh.x, 0.f) * d;
    float v1 = fmaxf(__uint_as_float(u.x & 0xffff0000u) * sc.y + sh.y, 0.f) * d;
    float v2 = fmaxf(__uint_as_float(u.y << 16) * sc.z + sh.z, 0.f) * d;
    float v3 = fmaxf(__uint_as_float(u.y & 0xffff0000u) * sc.w + sh.w, 0.f) * d;
    float m = fmaxf(fmaxf(v0, v1), fmaxf(v2, v3));
#pragma unroll
    for (int off = 1; off < 64; off <<= 1) m = fmaxf(m, __shfl_xor(m, off));
    float inv = m > 0.f ? 255.f / m : 0.f;
    unsigned int q0 = (unsigned int)(v0 * inv + 0.5f);
    unsigned int q1 = (unsigned int)(v1 * inv + 0.5f);
    unsigned int q2 = (unsigned int)(v2 * inv + 0.5f);
    unsigned int q3 = (unsigned int)(v3 * inv + 0.5f);
    *(unsigned int*)(y8 + (size_t)wv * 256 + lane * 4) = q0 | (q1 << 8) | (q2 << 16) | (q3 << 24);
    if (lane == 0) scaleY[wv] = m * (1.f / 255.f);
}

// ---- helpers: select SGPR-resident per-edge values into lanes ----
__device__ __forceinline__ int sel4i(const int* o, int g) {
    int a = (g & 1) ? o[1] : o[0];
    int b = (g & 1) ? o[3] : o[2];
    return (g & 2) ? b : a;
}
__device__ __forceinline__ float sel4f(const float* o, int g) {
    float a = (g & 1) ? o[1] : o[0];
    float b = (g & 1) ? o[3] : o[2];
    return (g & 2) ? b : a;
}
__device__ __forceinline__ int sel8i(const int* o, int g) {
    int a = sel4i(o, g), b = sel4i(o + 4, g);
    return (g & 4) ? b : a;
}
__device__ __forceinline__ float sel8f(const float* o, int g) {
    float a = sel4f(o, g), b = sel4f(o + 4, g);
    return (g & 4) ? b : a;
}

// ---- batch descriptor: scalar walk of 8 virtual edges (0 = self) ----
__device__ __forceinline__ void batch8(int b, int row, int rp, int cn,
                                       const int* __restrict__ csr,
                                       const float* __restrict__ rscale,
                                       int* ix, float* sc) {
#pragma unroll
    for (int j = 0; j < 8; j++) {
        int ve = b * 8 + j;
        int ci = min(ve, cn) - 1;
        ci = max(ci, 0);
        int idx = (ve == 0) ? row : csr[rp + ci];
        ix[j] = idx;
        sc[j] = (ve <= cn) ? rscale[idx] : 0.f;
    }
}

// ---- layer-2 gather: u8 256B rows, 4 edges per dwordx4 instruction ----
__global__ __launch_bounds__(256) void k_aggm256(const unsigned char* __restrict__ tab,
                                                 const float* __restrict__ rscale,
                                                 const float* __restrict__ dinv,
                                                 const int* __restrict__ rowptr,
                                                 const int* __restrict__ cnt,
                                                 const int* __restrict__ csr,
                                                 unsigned short* __restrict__ oa) {
    const int wid = threadIdx.x >> 6;
    const int lane = threadIdx.x & 63;
    const int wstep = (blockDim.x >> 6) * gridDim.x;
    const int l16 = lane & 15;
    const int g4 = lane >> 4;
    const int inner = l16 * 16;
    for (int row0 = blockIdx.x * (blockDim.x >> 6) + wid; row0 < NN; row0 += wstep) {
        const int row = __builtin_amdgcn_readfirstlane(row0);
        const int rp = __builtin_amdgcn_readfirstlane(rowptr[row]);
        const int cn = __builtin_amdgcn_readfirstlane(cnt[row]);
        float acc[16];
#pragma unroll
        for (int k = 0; k < 16; k++) acc[k] = 0.f;
        const int nbat = (cn + 8) >> 3;
        for (int b = 0; b < nbat; b++) {
            int ix[8];
            float sc[8];
            batch8(b, row, rp, cn, csr, rscale, ix, sc);
            int off[8];
#pragma unroll
            for (int j = 0; j < 8; j++) off[j] = ix[j] << 8;
            int o0 = sel4i(off, g4);
            int o1 = sel4i(off + 4, g4);
            float s0 = sel4f(sc, g4);
            float s1 = sel4f(sc + 4, g4);
            uint4 u0 = *(const uint4*)(tab + (size_t)(unsigned)o0 + inner);
            uint4 u1 = *(const uint4*)(tab + (size_t)(unsigned)o1 + inner);
            const unsigned int w0[4] = {u0.x, u0.y, u0.z, u0.w};
            const unsigned int w1[4] = {u1.x, u1.y, u1.z, u1.w};
#pragma unroll
            for (int jw = 0; jw < 4; jw++)
#pragma unroll
                for (int jb = 0; jb < 4; jb++) {
                    acc[jw * 4 + jb] += s0 * ub(w0[jw], jb);
                    acc[jw * 4 + jb] += s1 * ub(w1[jw], jb);
                }
        }
#pragma unroll
        for (int k = 0; k < 16; k++) {
            acc[k] += __shfl_xor(acc[k], 16);
            acc[k] += __shfl_xor(acc[k], 32);
        }
        const float d = dinv[row];
        if (lane < 16) {
            unsigned int w[8];
#pragma unroll
            for (int t = 0; t < 8; t++)
                w[t] = (unsigned int)f2bf(acc[2 * t] * d) |
                       ((unsigned int)f2bf(acc[2 * t + 1] * d) << 16);
            unsigned short* dst = oa + (size_t)row * 256 + lane * 16;
            *(uint4*)dst = make_uint4(w[0], w[1], w[2], w[3]);
            *(uint4*)(dst + 8) = make_uint4(w[4], w[5], w[6], w[7]);
        }
    }
}

// ---- layer-1 gather: s8 128B rows, 8 edges per dwordx4 instruction ----
__global__ __launch_bounds__(256) void k_aggm128(const unsigned char* __restrict__ tab,
                                                 const float* __restrict__ rscale,
                                                 const float* __restrict__ dinv,
                                                 const int* __restrict__ rowptr,
                                                 const int* __restrict__ cnt,
                                                 const int* __restrict__ csr,
                                                 unsigned short* __restrict__ oa) {
    const int wid = threadIdx.x >> 6;
    const int lane = threadIdx.x & 63;
    const int wstep = (blockDim.x >> 6) * gridDim.x;
    const int l8 = lane & 7;
    const int g8 = lane >> 3;
    const int inner = l8 * 16;
    for (int row0 = blockIdx.x * (blockDim.x >> 6) + wid; row0 < NN; row0 += wstep) {
        const int row = __builtin_amdgcn_readfirstlane(row0);
        const int rp = __builtin_amdgcn_readfirstlane(rowptr[row]);
        const int cn = __builtin_amdgcn_readfirstlane(cnt[row]);
        float acc[16];
#pragma unroll
        for (int k = 0; k < 16; k++) acc[k] = 0.f;
        const int nbat = (cn + 8) >> 3;
        for (int b = 0; b < nbat; b++) {
            int ix[8];
            float sc[8];
            batch8(b, row, rp, cn, csr, rscale, ix, sc);
            int off[8];
#pragma unroll
            for (int j = 0; j < 8; j++) off[j] = ix[j] << 7;
            int o0 = sel8i(off, g8);
            float s0 = sel8f(sc, g8);
            uint4 u0 = *(const uint4*)(tab + (size_t)(unsigned)o0 + inner);
            const unsigned int w0[4] = {u0.x, u0.y, u0.z, u0.w};
#pragma unroll
            for (int jw = 0; jw < 4; jw++)
#pragma unroll
                for (int jb = 0; jb < 4; jb++)
                    acc[jw * 4 + jb] += s0 * sbyte(w0[jw], jb);
        }
#pragma unroll
        for (int k = 0; k < 16; k++) {
            acc[k] += __shfl_xor(acc[k], 8);
            acc[k] += __shfl_xor(acc[k], 16);
            acc[k] += __shfl_xor(acc[k], 32);
        }
        const float d = dinv[row];
        if (lane < 8) {
            unsigned int w[8];
#pragma unroll
            for (int t = 0; t < 8; t++)
                w[t] = (unsigned int)f2bf(acc[2 * t] * d) |
                       ((unsigned int)f2bf(acc[2 * t + 1] * d) << 16);
            unsigned short* dst = oa + (size_t)row * 128 + lane * 16;
            *(uint4*)dst = make_uint4(w[0], w[1], w[2], w[3]);
            *(uint4*)(dst + 8) = make_uint4(w[4], w[5], w[6], w[7]);
        }
    }
}

// ---- GEMM: 64-row x 128-col tile; A bf16, W hi/lo; bias + BN stats fused ----
template <int K>
__global__ __launch_bounds__(256) void k_gemm(const unsigned short* __restrict__ A,
                                              const unsigned short* __restrict__ Wth,
                                              const unsigned short* __restrict__ Wtl,
                                              const float* __restrict__ bias,
                                              unsigned short* __restrict__ outX,
                                              float* __restrict__ s1,
                                              float* __restrict__ s2) {
    __shared__ unsigned short sA[64][40];
    const int t = threadIdx.x;
    const int w = t >> 6, lane = t & 63;
    const int quad = lane >> 4, l16 = lane & 15;
    const int rowBase = blockIdx.y * 64;
    const int colW = blockIdx.x * 128 + w * 32;
    f32x4 acc[4][2];
#pragma unroll
    for (int i = 0; i < 4; i++)
#pragma unroll
        for (int j = 0; j < 2; j++) acc[i][j] = (f32x4)0.f;

    for (int k0 = 0; k0 < K; k0 += 32) {
        int gr = rowBase + (t >> 2);
        int4 v = {0, 0, 0, 0};
        if (gr < NN) v = *(const int4*)(A + (size_t)gr * K + k0 + (t & 3) * 8);
        __syncthreads();
        *(int4*)&sA[t >> 2][(t & 3) * 8] = v;
        __syncthreads();
        const int kb = k0 >> 5;
        bf8 bh[2], bl[2];
#pragma unroll
        for (int j = 0; j < 2; j++) {
            size_t bo = ((size_t)(kb * 256 + colW + j * 16 + l16)) * 32 + quad * 8;
            bh[j] = *(const bf8*)(Wth + bo);
            bl[j] = *(const bf8*)(Wtl + bo);
        }
#pragma unroll
        for (int i = 0; i < 4; i++) {
            bf8 a = *(const bf8*)&sA[i * 16 + l16][quad * 8];
#pragma unroll
            for (int j = 0; j < 2; j++) {
                acc[i][j] = __builtin_amdgcn_mfma_f32_16x16x32_bf16(a, bh[j], acc[i][j], 0, 0, 0);
                acc[i][j] = __builtin_amdgcn_mfma_f32_16x16x32_bf16(a, bl[j], acc[i][j], 0, 0, 0);
            }
        }
    }
#pragma unroll
    for (int j = 0; j < 2; j++) {
        int col = colW + j * 16 + l16;
        float b = bias[col];
        float s1p = 0.f, s2p = 0.f;
#pragma unroll
        for (int i = 0; i < 4; i++) {
#pragma unroll
            for (int r = 0; r < 4; r++) {
                int row = rowBase + i * 16 + quad * 4 + r;
                if (row < NN) {
                    float v = acc[i][j][r] + b;
                    s1p += v;
                    s2p += v * v;
                    outX[(size_t)row * 256 + col] = f2bf(v);
                }
            }
        }
        s1p += __shfl_xor(s1p, 16); s1p += __shfl_xor(s1p, 32);
        s2p += __shfl_xor(s2p, 16); s2p += __shfl_xor(s2p, 32);
        if (quad == 0) {
            atomicAdd(&s1[col], s1p);
            atomicAdd(&s2[col], s2p);
        }
    }
}

// ---- layer-3 GEMM -> signed int8 H3 (64-col pad) + per-row scale ----
__global__ __launch_bounds__(256) void k_mgemm3(const unsigned short* __restrict__ y2,
                                                const unsigned short* __restrict__ Wth,
                                                const unsigned short* __restrict__ Wtl,
                                                unsigned char* __restrict__ H8,
                                                float* __restrict__ scaleH) {
    __shared__ unsigned short sA[128][40];
    __shared__ float sM[128][4];
    const int t = threadIdx.x;
    const int w = t >> 6, lane = t & 63;
    const int quad = lane >> 4, l16 = lane & 15;
    const int rowBase = blockIdx.x << 7;
    f32x4 acc[8];
#pragma unroll
    for (int i = 0; i < 8; i++) acc[i] = (f32x4)0.f;

    for (int k0 = 0; k0 < 256; k0 += 32) {
        const int kb = k0 >> 5;
        int id0 = t, id1 = t + 256;
        int gr0 = rowBase + (id0 >> 2), gr1 = rowBase + (id1 >> 2);
        int4 zz = {0, 0, 0, 0};
        int4 v0 = (gr0 < NN) ? *(const int4*)(y2 + (size_t)gr0 * 256 + k0 + (id0 & 3) * 8) : zz;
        int4 v1 = (gr1 < NN) ? *(const int4*)(y2 + (size_t)gr1 * 256 + k0 + (id1 & 3) * 8) : zz;
        __syncthreads();
        *(int4*)&sA[id0 >> 2][(id0 & 3) * 8] = v0;
        *(int4*)&sA[id1 >> 2][(id1 & 3) * 8] = v1;
        __syncthreads();
        size_t bo = ((size_t)(kb * 64 + w * 16 + l16)) * 32 + quad * 8;
        bf8 bh = *(const bf8*)(Wth + bo);
        bf8 bl = *(const bf8*)(Wtl + bo);
#pragma unroll
        for (int i = 0; i < 8; i++) {
            bf8 a = *(const bf8*)&sA[i * 16 + l16][quad * 8];
            acc[i] = __builtin_amdgcn_mfma_f32_16x16x32_bf16(a, bh, acc[i], 0, 0, 0);
            acc[i] = __builtin_amdgcn_mfma_f32_16x16x32_bf16(a, bl, acc[i], 0, 0, 0);
        }
    }
#pragma unroll
    for (int i = 0; i < 8; i++) {
#pragma unroll
        for (int r = 0; r < 4; r++) {
            float m = fabsf(acc[i][r]);
            m = fmaxf(m, __shfl_xor(m, 1));
            m = fmaxf(m, __shfl_xor(m, 2));
            m = fmaxf(m, __shfl_xor(m, 4));
            m = fmaxf(m, __shfl_xor(m, 8));
            if (l16 == 0) sM[i * 16 + quad * 4 + r][w] = m;
        }
    }
    __syncthreads();
    const int col = w * 16 + l16;
#pragma unroll
    for (int i = 0; i < 8; i++) {
#pragma unroll
        for (int r = 0; r < 4; r++) {
            int rloc = i * 16 + quad * 4 + r;
            int row = rowBase + rloc;
            float m = fmaxf(fmaxf(sM[rloc][0], sM[rloc][1]), fmaxf(sM[rloc][2], sM[rloc][3]));
            float inv = m > 0.f ? 127.f / m : 0.f;
            if (row < NN) {
                int q = (int)rintf(acc[i][r] * inv);
                H8[(size_t)row * 64 + col] = (unsigned char)(q & 0xff);
                if (w == 0 && l16 == 0) scaleH[row] = m * (1.f / 127.f);
            }
        }
    }
}

// ---- final gather: s8 64B rows, 8 edges per dwordx2 instruction ----
__global__ __launch_bounds__(256) void k_aggfbm(const unsigned char* __restrict__ tab,
                                                const float* __restrict__ rscale,
                                                const float* __restrict__ dinv,
                                                const int* __restrict__ rowptr,
                                                const int* __restrict__ cnt,
                                                const int* __restrict__ csr,
                                                const float* __restrict__ bias,
                                                float* __restrict__ out) {
    const int wid = threadIdx.x >> 6;
    const int lane = threadIdx.x & 63;
    const int wstep = (blockDim.x >> 6) * gridDim.x;
    const int l8 = lane & 7;
    const int g8 = lane >> 3;
    const int inner = l8 * 8;
    for (int row0 = blockIdx.x * (blockDim.x >> 6) + wid; row0 < NN; row0 += wstep) {
        const int row = __builtin_amdgcn_readfirstlane(row0);
        const int rp = __builtin_amdgcn_readfirstlane(rowptr[row]);
        const int cn = __builtin_amdgcn_readfirstlane(cnt[row]);
        float acc[8];
#pragma unroll
        for (int k = 0; k < 8; k++) acc[k] = 0.f;
        const int nbat = (cn + 8) >> 3;
        for (int b = 0; b < nbat; b++) {
            int ix[8];
            float sc[8];
            batch8(b, row, rp, cn, csr, rscale, ix, sc);
            int off[8];
#pragma unroll
            for (int j = 0; j < 8; j++) off[j] = ix[j] << 6;
            int o0 = sel8i(off, g8);
            float s0 = sel8f(sc, g8);
            uint2 u0 = *(const uint2*)(tab + (size_t)(unsigned)o0 + inner);
#pragma unroll
            for (int jb = 0; jb < 4; jb++) {
                acc[jb] += s0 * sbyte(u0.x, jb);
                acc[4 + jb] += s0 * sbyte(u0.y, jb);
            }
        }
#pragma unroll
        for (int k = 0; k < 8; k++) {
            acc[k] += __shfl_xor(acc[k], 8);
            acc[k] += __shfl_xor(acc[k], 16);
            acc[k] += __shfl_xor(acc[k], 32);
        }
        const float d = dinv[row];
        const int f0 = l8 * 8;
        if (lane < 8 && f0 < FOUT) {
            float4 oA, oB;
            oA.x = acc[0] * d + bias[f0 + 0];
            oA.y = acc[1] * d + bias[f0 + 1];
            oA.z = acc[2] * d + bias[f0 + 2];
            oA.w = acc[3] * d + bias[f0 + 3];
            oB.x = acc[4] * d + bias[f0 + 4];
            oB.y = acc[5] * d + bias[f0 + 5];
            oB.z = acc[6] * d + bias[f0 + 6];
            oB.w = acc[7] * d + bias[f0 + 7];
            float* dst = out + (size_t)row * FOUT + f0;
            *(float4*)dst = oA;
            *(float4*)(dst + 4) = oB;
        }
    }
}

__global__ void k_bnfold(const float* __restrict__ s1, const float* __restrict__ s2,
                         const float* __restrict__ g, const float* __restrict__ be,
                         float* __restrict__ scale, float* __restrict__ shift) {
    int c = threadIdx.x;
    if (c < 256) {
        float mean = s1[c] * (1.f / NN);
        float var = s2[c] * (1.f / NN) - mean * mean;
        float sc = g[c] * rsqrtf(var + EPSV);
        scale[c] = sc;
        shift[c] = be[c] - mean * sc;
    }
}

// ---- BN+ReLU bf16->bf16 table (x dinv) — layer-2 output for mgemm3 ----
__global__ void k_bnr(const unsigned short* __restrict__ x,
                      const float* __restrict__ scale, const float* __restrict__ shift,
                      const float* __restrict__ dinv, unsigned short* __restrict__ oy) {
    int i = blockIdx.x * blockDim.x + threadIdx.x;
    if (i >= NN * 128) return;
    int row = i >> 7;
    int c = (i & 127) * 2;
    unsigned int u = ((const unsigned int*)x)[i];
    float x0 = __uint_as_float(u << 16);
    float x1 = __uint_as_float(u & 0xffff0000u);
    float d = dinv[row];
    float v0 = fmaxf(x0 * scale[c + 0] + shift[c + 0], 0.f) * d;
    float v1 = fmaxf(x1 * scale[c + 1] + shift[c + 1], 0.f) * d;
    ((unsigned int*)oy)[i] = (unsigned int)f2bf(v0) | ((unsigned int)f2bf(v1) << 16);
}

extern "C" void kernel_launch(void* const* d_in, const int* in_sizes, int n_in,
                              void* d_out, int out_size, void* d_ws, size_t ws_size,
                              hipStream_t stream) {
    const int* ei = (const int*)d_in[0];
    const float* z = (const float*)d_in[1];
    const float* W1 = (const float*)d_in[2];
    const float* b1 = (const float*)d_in[3];
    const float* g1 = (const float*)d_in[4];
    const float* be1 = (const float*)d_in[5];
    const float* W2 = (const float*)d_in[6];
    const float* b2 = (const float*)d_in[7];
    const float* g2 = (const float*)d_in[8];
    const float* be2 = (const float*)d_in[9];
    const float* W3 = (const float*)d_in[10];
    const float* b3 = (const float*)d_in[11];
    float* out = (float*)d_out;

    char* w = (char*)d_ws;
    size_t o = 0;
    auto take = [&](size_t bytes) {
        char* p = w + o;
        o = (o + bytes + 255) & ~(size_t)255;
        return p;
    };
    int* cnt = (int*)take((size_t)NN * 4);
    int* rowptr = (int*)take((size_t)NN * 4);
    int* gcur = (int*)take(NBKT * 4);
    int* bbase = (int*)take(NBKT * 4);
    int* csr = (int*)take((size_t)NE * 4 + 256);
    unsigned int* staging = (unsigned int*)take((size_t)NBKT * CAPB * 4);
    float* dinv = (float*)take((size_t)NN * 4);
    float* stat = (float*)take(4 * 256 * 4);
    float* sc1 = (float*)take(256 * 4);
    float* sh1 = (float*)take(256 * 4);
    float* sc2 = (float*)take(256 * 4);
    float* sh2 = (float*)take(256 * 4);
    unsigned short* Wt1h = (unsigned short*)take(256 * 128 * 2);
    unsigned short* Wt1l = (unsigned short*)take(256 * 128 * 2);
    unsigned short* Wt2h = (unsigned short*)take(256 * 256 * 2);
    unsigned short* Wt2l = (unsigned short*)take(256 * 256 * 2);
    unsigned short* Wt3h = (unsigned short*)take(64 * 256 * 2);
    unsigned short* Wt3l = (unsigned short*)take(64 * 256 * 2);
    unsigned char* zp8 = (unsigned char*)take((size_t)NN * FIN);
    unsigned char* y1_8 = (unsigned char*)take((size_t)NN * FH);
    unsigned char* H8 = (unsigned char*)take((size_t)NN * 64);
    float* scaleZ = (float*)take((size_t)NN * 4);
    float* scaleY = (float*)take((size_t)NN * 4);
    float* scaleH = (float*)take((size_t)NN * 4);
    unsigned short* P1 = (unsigned short*)take((size_t)NN * 256 * 2);
    unsigned short* P2 = (unsigned short*)take((size_t)NN * 512 * 2);

    unsigned short* a1 = P1;
    unsigned short* x1 = P2;
    unsigned short* a2 = P2 + (size_t)NN * 256;
    unsigned short* x2 = P1;
    unsigned short* y2 = P2;
    float* s1a = stat, *s2a = stat + 256, *s1b = stat + 512, *s2b = stat + 768;

    hipMemsetAsync(gcur, 0, NBKT * 4, stream);
    hipMemsetAsync(stat, 0, 4 * 256 * 4, stream);

    // CSR build (two-level counting sort; dtype flag computed inline)
    k_bin<<<(NE + CHNK - 1) / CHNK, 256, 0, stream>>>(ei, gcur, staging);
    k_bucketscan<<<1, 256, 0, stream>>>(gcur, bbase);
    k_build<<<NBKT, 256, 0, stream>>>(staging, gcur, bbase, cnt, dinv, rowptr, csr);

    k_wprep<<<(256 * 128 + 256 * 256 + 64 * 256 + 255) / 256, 256, 0, stream>>>(
        W1, Wt1h, Wt1l, W2, Wt2h, Wt2l, W3, Wt3h, Wt3l);

    const int GR = (NN + 63) / 64;
    const int WV = (NN + 3) / 4;

    // layer 1
    k_zpb8<<<WV, 256, 0, stream>>>(z, dinv, zp8, scaleZ);
    k_aggm128<<<2560, 256, 0, stream>>>(zp8, scaleZ, dinv, rowptr, cnt, csr, a1);
    k_gemm<128><<<dim3(2, GR), 256, 0, stream>>>(a1, Wt1h, Wt1l, b1, x1, s1a, s2a);
    k_bnfold<<<1, 256, 0, stream>>>(s1a, s2a, g1, be1, sc1, sh1);
    k_bnr8<<<WV, 256, 0, stream>>>(x1, sc1, sh1, dinv, y1_8, scaleY);

    // layer 2
    k_aggm256<<<2560, 256, 0, stream>>>(y1_8, scaleY, dinv, rowptr, cnt, csr, a2);
    k_gemm<256><<<dim3(2, GR), 256, 0, stream>>>(a2, Wt2h, Wt2l, b2, x2, s1b, s2b);
    k_bnfold<<<1, 256, 0, stream>>>(s1b, s2b, g2, be2, sc2, sh2);
    k_bnr<<<(NN * 128 + 255) / 256, 256, 0, stream>>>(x2, sc2, sh2, dinv, y2);

    // layer 3
    k_mgemm3<<<NBKT, 256, 0, stream>>>(y2, Wt3h, Wt3l, H8, scaleH);
    k_aggfbm<<<2560, 256, 0, stream>>>(H8, scaleH, dinv, rowptr, cnt, csr, b3, out);
}

// Round 6
// 995.963 us; speedup vs baseline: 2.0457x; 1.1677x over previous
//
#include <hip/hip_runtime.h>

// GCN 3-layer: N=100000, E=3200000, 128 -> 256 -> 256 -> 40
// Round 13: dual-row interleaved gathers (r1 scalar-walk structure, two rows
// per wave, ping-pong batches with static double buffers) -- hides the per-row
// serial chain rowptr->cnt->csr->rscale/payload that r3's within-row pipeline
// could not (pipe drained at every row boundary). Masked full batches replace
// the scalar tail. Plus: k_bnfold folded into k_bnr8; k_bnr folded into
// k_mgemm3 A-staging (saves ~100MB traffic + 3 launches).
// Tables: zp signed i8 (128B rows), y1 unsigned i8 (256B), H3 signed i8 (64B).

#define NN   100000
#define NE   3200000
#define FIN  128
#define FH   256
#define FOUT 40
#define EPSV 1e-5f

#define BSH   7
#define NBKT  ((NN + 127) >> BSH)  // 782
#define CAPB  8192
#define CHNK  4096

typedef __attribute__((ext_vector_type(8))) short bf8;
typedef __attribute__((ext_vector_type(4))) float f32x4;

__device__ __forceinline__ unsigned short f2bf(float x) {
    unsigned int u = __float_as_uint(x);
    unsigned int r = u + 0x7fffu + ((u >> 16) & 1u);
    return (unsigned short)(r >> 16);
}
__device__ __forceinline__ float bf2f(unsigned short h) {
    return __uint_as_float(((unsigned int)h) << 16);
}
__device__ __forceinline__ void f2bf2(float x, unsigned short& hi, unsigned short& lo) {
    unsigned short h = f2bf(x);
    hi = h;
    lo = f2bf(x - bf2f(h));
}
__device__ __forceinline__ float ub(unsigned int u, int k) {
    return (float)((u >> (8 * k)) & 0xffu);
}
__device__ __forceinline__ float sbyte(unsigned int u, int k) {
    return (float)(int)(signed char)((u >> (8 * k)) & 0xffu);
}

// ---- pass 1: bin edges by dst>>7 into fixed-slot staging (flag computed inline) ----
__global__ __launch_bounds__(256) void k_bin(const int* __restrict__ ei,
                                             int* __restrict__ gcur,
                                             unsigned int* __restrict__ staging) {
    __shared__ int hcnt[NBKT];
    __shared__ int hbase[NBKT];
    __shared__ int sflag;
    const int tid = threadIdx.x;
    const int e0 = blockIdx.x * CHNK;
    for (int b = tid; b < NBKT; b += 256) hcnt[b] = 0;
    if (tid == 0) {
        int zz = 0;
        for (int i = 0; i < 64; i++) zz |= ei[2 * i + 1];
        sflag = (zz == 0) ? 1 : 0;
    }
    __syncthreads();
    const int f = sflag;
    for (int r = 0; r < CHNK / 256; r++) {
        int e = e0 + r * 256 + tid;
        if (e < NE) {
            int d = f ? ei[2 * (NE + e)] : ei[NE + e];
            atomicAdd(&hcnt[d >> BSH], 1);
        }
    }
    __syncthreads();
    for (int b = tid; b < NBKT; b += 256) {
        int c = hcnt[b];
        hbase[b] = c ? atomicAdd(&gcur[b], c) : 0;
    }
    __syncthreads();
    for (int b = tid; b < NBKT; b += 256) hcnt[b] = 0;
    __syncthreads();
    for (int r = 0; r < CHNK / 256; r++) {
        int e = e0 + r * 256 + tid;
        if (e < NE) {
            int s = f ? ei[2 * e] : ei[e];
            int d = f ? ei[2 * (NE + e)] : ei[NE + e];
            int b = d >> BSH;
            int loc = atomicAdd(&hcnt[b], 1);
            int pos = hbase[b] + loc;
            if (pos < CAPB)
                staging[(size_t)b * CAPB + pos] =
                    (unsigned int)s | ((unsigned int)(d & 127) << 17);
        }
    }
}

__global__ void k_bucketscan(const int* __restrict__ gcur, int* __restrict__ bbase) {
    __shared__ int sb2[2][256];
    int t = threadIdx.x;
    int base = t * 4;
    int v0 = (base + 0 < NBKT) ? gcur[base + 0] : 0;
    int v1 = (base + 1 < NBKT) ? gcur[base + 1] : 0;
    int v2 = (base + 2 < NBKT) ? gcur[base + 2] : 0;
    int v3 = (base + 3 < NBKT) ? gcur[base + 3] : 0;
    int s0 = v0, s1 = s0 + v1, s2 = s1 + v2, s3 = s2 + v3;
    sb2[0][t] = s3;
    __syncthreads();
    int pi = 0;
    for (int off = 1; off < 256; off <<= 1) {
        int x = sb2[pi][t];
        if (t >= off) x += sb2[pi][t - off];
        sb2[pi ^ 1][t] = x;
        __syncthreads();
        pi ^= 1;
    }
    int excl = sb2[pi][t] - s3;
    if (base + 0 < NBKT) bbase[base + 0] = excl;
    if (base + 1 < NBKT) bbase[base + 1] = excl + s0;
    if (base + 2 < NBKT) bbase[base + 2] = excl + s1;
    if (base + 3 < NBKT) bbase[base + 3] = excl + s2;
}

// ---- pass 2: per-bucket build of cnt/dinv/rowptr/csr ----
__global__ __launch_bounds__(256) void k_build(const unsigned int* __restrict__ staging,
                                               const int* __restrict__ gcur,
                                               const int* __restrict__ bbase,
                                               int* __restrict__ cntg,
                                               float* __restrict__ dinv,
                                               int* __restrict__ rowptr,
                                               int* __restrict__ csr) {
    __shared__ int lcnt[128];
    __shared__ int lscan[2][128];
    __shared__ int lcur[128];
    const int tid = threadIdx.x;
    const int b = blockIdx.x;
    const int tot = min(gcur[b], CAPB);
    const int bb = bbase[b];
    const unsigned int* st = staging + (size_t)b * CAPB;
    if (tid < 128) lcnt[tid] = 0;
    __syncthreads();
    for (int i = tid; i < tot; i += 256) {
        unsigned int v = st[i];
        atomicAdd(&lcnt[v >> 17], 1);
    }
    __syncthreads();
    int pi = 0;
    if (tid < 128) lscan[0][tid] = lcnt[tid];
    __syncthreads();
    for (int off = 1; off < 128; off <<= 1) {
        if (tid < 128) {
            int x = lscan[pi][tid];
            if (tid >= off) x += lscan[pi][tid - off];
            lscan[pi ^ 1][tid] = x;
        }
        __syncthreads();
        pi ^= 1;
    }
    if (tid < 128) {
        int c = lcnt[tid];
        int excl = lscan[pi][tid] - c;
        lcur[tid] = excl;
        int node = (b << BSH) + tid;
        if (node < NN) {
            cntg[node] = c;
            dinv[node] = rsqrtf((float)(c + 1));
            rowptr[node] = bb + excl;
        }
    }
    __syncthreads();
    for (int i = tid; i < tot; i += 256) {
        unsigned int v = st[i];
        int pos = atomicAdd(&lcur[v >> 17], 1);
        csr[bb + pos] = (int)(v & 0x1ffffu);
    }
}

// ---- fused weight prep: all three matrices, fragment-contiguous hi/lo bf16 ----
// Wt[((k>>5)*MP + m)*32 + (k&31)]
__global__ void k_wprep(const float* __restrict__ W1, unsigned short* __restrict__ W1h,
                        unsigned short* __restrict__ W1l,
                        const float* __restrict__ W2, unsigned short* __restrict__ W2h,
                        unsigned short* __restrict__ W2l,
                        const float* __restrict__ W3, unsigned short* __restrict__ W3h,
                        unsigned short* __restrict__ W3l) {
    int idx = blockIdx.x * blockDim.x + threadIdx.x;
    const float* W;
    unsigned short *Wh, *Wl;
    int K, M, MP;
    if (idx < 256 * 128) {
        W = W1; Wh = W1h; Wl = W1l; K = 128; M = 256; MP = 256;
    } else if (idx < 256 * 128 + 256 * 256) {
        idx -= 256 * 128;
        W = W2; Wh = W2h; Wl = W2l; K = 256; M = 256; MP = 256;
    } else if (idx < 256 * 128 + 256 * 256 + 64 * 256) {
        idx -= 256 * 128 + 256 * 256;
        W = W3; Wh = W3h; Wl = W3l; K = 256; M = 40; MP = 64;
    } else {
        return;
    }
    int m = idx / K, k = idx - m * K;
    float v = (m < M) ? W[(size_t)k * M + m] : 0.f;
    unsigned short h, l;
    f2bf2(v, h, l);
    size_t dst = ((size_t)(k >> 5) * MP + m) * 32 + (k & 31);
    Wh[dst] = h;
    Wl[dst] = l;
}

// ---- z * dinv -> signed int8 rows + per-row scale (wave per row) ----
__global__ __launch_bounds__(256) void k_zpb8(const float* __restrict__ z,
                                              const float* __restrict__ dinv,
                                              unsigned char* __restrict__ zp8,
                                              float* __restrict__ scaleZ) {
    int wv = (blockIdx.x * blockDim.x + threadIdx.x) >> 6;
    int lane = threadIdx.x & 63;
    if (wv >= NN) return;
    float2 v = *(const float2*)(z + (size_t)wv * FIN + lane * 2);
    float d = dinv[wv];
    float a0 = v.x * d, a1 = v.y * d;
    float m = fmaxf(fabsf(a0), fabsf(a1));
#pragma unroll
    for (int off = 1; off < 64; off <<= 1) m = fmaxf(m, __shfl_xor(m, off));
    float inv = m > 0.f ? 127.f / m : 0.f;
    int q0 = (int)rintf(a0 * inv), q1 = (int)rintf(a1 * inv);
    unsigned short pk = (unsigned short)((q0 & 0xff) | ((q1 & 0xff) << 8));
    *(unsigned short*)(zp8 + (size_t)wv * FIN + lane * 2) = pk;
    if (lane == 0) scaleZ[wv] = m * (1.f / 127.f);
}

// ---- BN(from stats)+ReLU+dinv -> unsigned int8 rows + per-row scale ----
__global__ __launch_bounds__(256) void k_bnr8(const unsigned short* __restrict__ x,
                                              const float* __restrict__ s1,
                                              const float* __restrict__ s2,
                                              const float* __restrict__ g,
                                              const float* __restrict__ be,
                                              const float* __restrict__ dinv,
                                              unsigned char* __restrict__ y8,
                                              float* __restrict__ scaleY) {
    int wv = (blockIdx.x * blockDim.x + threadIdx.x) >> 6;
    int lane = threadIdx.x & 63;
    if (wv >= NN) return;
    float4 m1 = *(const float4*)(s1 + lane * 4);
    float4 m2 = *(const float4*)(s2 + lane * 4);
    float4 gg = *(const float4*)(g + lane * 4);
    float4 bb = *(const float4*)(be + lane * 4);
    float mx = m1.x * (1.f / NN), my = m1.y * (1.f / NN);
    float mz = m1.z * (1.f / NN), mw = m1.w * (1.f / NN);
    float scx = gg.x * rsqrtf(m2.x * (1.f / NN) - mx * mx + EPSV);
    float scy = gg.y * rsqrtf(m2.y * (1.f / NN) - my * my + EPSV);
    float scz = gg.z * rsqrtf(m2.z * (1.f / NN) - mz * mz + EPSV);
    float scw = gg.w * rsqrtf(m2.w * (1.f / NN) - mw * mw + EPSV);
    float shx = bb.x - mx * scx, shy = bb.y - my * scy;
    float shz = bb.z - mz * scz, shw = bb.w - mw * scw;
    uint2 u = *(const uint2*)(x + (size_t)wv * 256 + lane * 4);
    float d = dinv[wv];
    float v0 = fmaxf(__uint_as_float(u.x << 16) * scx + shx, 0.f) * d;
    float v1 = fmaxf(__uint_as_float(u.x & 0xffff0000u) * scy + shy, 0.f) * d;
    float v2 = fmaxf(__uint_as_float(u.y << 16) * scz + shz, 0.f) * d;
    float v3 = fmaxf(__uint_as_float(u.y & 0xffff0000u) * scw + shw, 0.f) * d;
    float m = fmaxf(fmaxf(v0, v1), fmaxf(v2, v3));
#pragma unroll
    for (int off = 1; off < 64; off <<= 1) m = fmaxf(m, __shfl_xor(m, off));
    float inv = m > 0.f ? 255.f / m : 0.f;
    unsigned int q0 = (unsigned int)(v0 * inv + 0.5f);
    unsigned int q1 = (unsigned int)(v1 * inv + 0.5f);
    unsigned int q2 = (unsigned int)(v2 * inv + 0.5f);
    unsigned int q3 = (unsigned int)(v3 * inv + 0.5f);
    *(unsigned int*)(y8 + (size_t)wv * 256 + lane * 4) = q0 | (q1 << 8) | (q2 << 16) | (q3 << 24);
    if (lane == 0) scaleY[wv] = m * (1.f / 255.f);
}

// ---- dual-row int8 gather: two rows per wave, ping-pong batches ----
// F=128: signed, ushort/lane; F=256: unsigned, uint/lane. Scalar CSR walk
// (SGPR idx/scale); masked full batches (scale 0) replace the scalar tail.
template <int F, bool SIGNED>
__global__ __launch_bounds__(256) void k_agg2(const unsigned char* __restrict__ tab,
                                              const float* __restrict__ rscale,
                                              const float* __restrict__ dinv,
                                              const int* __restrict__ rowptr,
                                              const int* __restrict__ cnt,
                                              const int* __restrict__ csr,
                                              unsigned short* __restrict__ oa) {
    const int wid = threadIdx.x >> 6;
    const int lane = threadIdx.x & 63;
    const int wstep = (blockDim.x >> 6) * gridDim.x;
    constexpr int B = F / 64;
    const int off = lane * B;
    const int NP = (NN + 1) / 2;

    auto LOADB = [&](int row, int rp, int cn, int b, float* sc, unsigned int* u) {
#pragma unroll
        for (int j = 0; j < 8; j++) {
            int e = b * 8 + j;
            int ci = (e < cn) ? csr[rp + e] : row;
            sc[j] = (e < cn) ? rscale[ci] : 0.f;
            if constexpr (B == 4)
                u[j] = *(const unsigned int*)(tab + (size_t)ci * F + off);
            else
                u[j] = *(const unsigned short*)(tab + (size_t)ci * F + off);
        }
    };
    auto FMAB = [&](float* acc, const float* sc, const unsigned int* u) {
#pragma unroll
        for (int j = 0; j < 8; j++) {
            if constexpr (B == 4) {
                acc[0] += sc[j] * (SIGNED ? sbyte(u[j], 0) : ub(u[j], 0));
                acc[1] += sc[j] * (SIGNED ? sbyte(u[j], 1) : ub(u[j], 1));
                acc[2] += sc[j] * (SIGNED ? sbyte(u[j], 2) : ub(u[j], 2));
                acc[3] += sc[j] * (SIGNED ? sbyte(u[j], 3) : ub(u[j], 3));
            } else {
                acc[0] += sc[j] * (SIGNED ? sbyte(u[j], 0) : ub(u[j], 0));
                acc[1] += sc[j] * (SIGNED ? sbyte(u[j], 1) : ub(u[j], 1));
            }
        }
    };
    auto SELF = [&](int row, float* acc) {
        float s = rscale[row];
        if constexpr (B == 4) {
            unsigned int u = *(const unsigned int*)(tab + (size_t)row * F + off);
            acc[0] = s * (SIGNED ? sbyte(u, 0) : ub(u, 0));
            acc[1] = s * (SIGNED ? sbyte(u, 1) : ub(u, 1));
            acc[2] = s * (SIGNED ? sbyte(u, 2) : ub(u, 2));
            acc[3] = s * (SIGNED ? sbyte(u, 3) : ub(u, 3));
        } else {
            unsigned int u = *(const unsigned short*)(tab + (size_t)row * F + off);
            acc[0] = s * (SIGNED ? sbyte(u, 0) : ub(u, 0));
            acc[1] = s * (SIGNED ? sbyte(u, 1) : ub(u, 1));
        }
    };
    auto STORE = [&](int row, const float* acc) {
        float d = dinv[row];
        size_t p = (size_t)row * F + off;
        if constexpr (B == 4) {
            uint2 o;
            o.x = (unsigned int)f2bf(acc[0] * d) | ((unsigned int)f2bf(acc[1] * d) << 16);
            o.y = (unsigned int)f2bf(acc[2] * d) | ((unsigned int)f2bf(acc[3] * d) << 16);
            *(uint2*)(oa + p) = o;
        } else {
            *(unsigned int*)(oa + p) =
                (unsigned int)f2bf(acc[0] * d) | ((unsigned int)f2bf(acc[1] * d) << 16);
        }
    };

    for (int p0 = blockIdx.x * (blockDim.x >> 6) + wid; p0 < NP; p0 += wstep) {
        const int rA = __builtin_amdgcn_readfirstlane(p0 * 2);
        const int rB = min(rA + 1, NN - 1);
        const int rpA = __builtin_amdgcn_readfirstlane(rowptr[rA]);
        const int cnA = __builtin_amdgcn_readfirstlane(cnt[rA]);
        const int rpB = __builtin_amdgcn_readfirstlane(rowptr[rB]);
        const int cnB = __builtin_amdgcn_readfirstlane(cnt[rB]);
        float accA[B], accB[B];
        SELF(rA, accA);
        SELF(rB, accB);
        const int nb = max((cnA + 7) >> 3, (cnB + 7) >> 3);
        if (nb > 0) {
            float scA0[8], scB0[8], scA1[8], scB1[8];
            unsigned int uA0[8], uB0[8], uA1[8], uB1[8];
            LOADB(rA, rpA, cnA, 0, scA0, uA0);
            LOADB(rB, rpB, cnB, 0, scB0, uB0);
            int b = 0;
            while (true) {
                bool more = (b + 1 < nb);
                if (more) LOADB(rA, rpA, cnA, b + 1, scA1, uA1);
                FMAB(accA, scA0, uA0);
                if (more) LOADB(rB, rpB, cnB, b + 1, scB1, uB1);
                FMAB(accB, scB0, uB0);
                if (!more) break;
                b++;
                bool more2 = (b + 1 < nb);
                if (more2) LOADB(rA, rpA, cnA, b + 1, scA0, uA0);
                FMAB(accA, scA1, uA1);
                if (more2) LOADB(rB, rpB, cnB, b + 1, scB0, uB0);
                FMAB(accB, scB1, uB1);
                if (!more2) break;
                b++;
            }
        }
        STORE(rA, accA);
        if (rB != rA) STORE(rB, accB);
    }
}

// ---- GEMM: 64-row x 128-col tile; A bf16, W hi/lo; bias + BN stats fused ----
template <int K>
__global__ __launch_bounds__(256) void k_gemm(const unsigned short* __restrict__ A,
                                              const unsigned short* __restrict__ Wth,
                                              const unsigned short* __restrict__ Wtl,
                                              const float* __restrict__ bias,
                                              unsigned short* __restrict__ outX,
                                              float* __restrict__ s1,
                                              float* __restrict__ s2) {
    __shared__ unsigned short sA[64][40];
    const int t = threadIdx.x;
    const int w = t >> 6, lane = t & 63;
    const int quad = lane >> 4, l16 = lane & 15;
    const int rowBase = blockIdx.y * 64;
    const int colW = blockIdx.x * 128 + w * 32;
    f32x4 acc[4][2];
#pragma unroll
    for (int i = 0; i < 4; i++)
#pragma unroll
        for (int j = 0; j < 2; j++) acc[i][j] = (f32x4)0.f;

    for (int k0 = 0; k0 < K; k0 += 32) {
        int gr = rowBase + (t >> 2);
        int4 v = {0, 0, 0, 0};
        if (gr < NN) v = *(const int4*)(A + (size_t)gr * K + k0 + (t & 3) * 8);
        __syncthreads();
        *(int4*)&sA[t >> 2][(t & 3) * 8] = v;
        __syncthreads();
        const int kb = k0 >> 5;
        bf8 bh[2], bl[2];
#pragma unroll
        for (int j = 0; j < 2; j++) {
            size_t bo = ((size_t)(kb * 256 + colW + j * 16 + l16)) * 32 + quad * 8;
            bh[j] = *(const bf8*)(Wth + bo);
            bl[j] = *(const bf8*)(Wtl + bo);
        }
#pragma unroll
        for (int i = 0; i < 4; i++) {
            bf8 a = *(const bf8*)&sA[i * 16 + l16][quad * 8];
#pragma unroll
            for (int j = 0; j < 2; j++) {
                acc[i][j] = __builtin_amdgcn_mfma_f32_16x16x32_bf16(a, bh[j], acc[i][j], 0, 0, 0);
                acc[i][j] = __builtin_amdgcn_mfma_f32_16x16x32_bf16(a, bl[j], acc[i][j], 0, 0, 0);
            }
        }
    }
#pragma unroll
    for (int j = 0; j < 2; j++) {
        int col = colW + j * 16 + l16;
        float b = bias[col];
        float s1p = 0.f, s2p = 0.f;
#pragma unroll
        for (int i = 0; i < 4; i++) {
#pragma unroll
            for (int r = 0; r < 4; r++) {
                int row = rowBase + i * 16 + quad * 4 + r;
                if (row < NN) {
                    float v = acc[i][j][r] + b;
                    s1p += v;
                    s2p += v * v;
                    outX[(size_t)row * 256 + col] = f2bf(v);
                }
            }
        }
        s1p += __shfl_xor(s1p, 16); s1p += __shfl_xor(s1p, 32);
        s2p += __shfl_xor(s2p, 16); s2p += __shfl_xor(s2p, 32);
        if (quad == 0) {
            atomicAdd(&s1[col], s1p);
            atomicAdd(&s2[col], s2p);
        }
    }
}

__device__ __forceinline__ unsigned int bn2(unsigned int w, float sc0, float sh0,
                                            float sc1, float sh1, float d) {
    float x0 = __uint_as_float(w << 16);
    float x1 = __uint_as_float(w & 0xffff0000u);
    float y0 = fmaxf(x0 * sc0 + sh0, 0.f) * d;
    float y1 = fmaxf(x1 * sc1 + sh1, 0.f) * d;
    return (unsigned int)f2bf(y0) | ((unsigned int)f2bf(y1) << 16);
}

// ---- layer-3 GEMM with fused BN+ReLU on A-staging -> signed int8 H3 + scale ----
__global__ __launch_bounds__(256) void k_mgemm3(const unsigned short* __restrict__ x2,
                                                const float* __restrict__ s1,
                                                const float* __restrict__ s2,
                                                const float* __restrict__ g,
                                                const float* __restrict__ be,
                                                const unsigned short* __restrict__ Wth,
                                                const unsigned short* __restrict__ Wtl,
                                                const float* __restrict__ dinv,
                                                unsigned char* __restrict__ H8,
                                                float* __restrict__ scaleH) {
    __shared__ unsigned short sA[128][40];
    __shared__ float sM[128][4];
    __shared__ float sSC[256];
    __shared__ float sSH[256];
    const int t = threadIdx.x;
    const int w = t >> 6, lane = t & 63;
    const int quad = lane >> 4, l16 = lane & 15;
    const int rowBase = blockIdx.x << 7;
    {
        float mean = s1[t] * (1.f / NN);
        float var = s2[t] * (1.f / NN) - mean * mean;
        float sc = g[t] * rsqrtf(var + EPSV);
        sSC[t] = sc;
        sSH[t] = be[t] - mean * sc;
    }
    f32x4 acc[8];
#pragma unroll
    for (int i = 0; i < 8; i++) acc[i] = (f32x4)0.f;

    const int gr0 = rowBase + (t >> 2);
    const int gr1 = gr0 + 64;
    const float dA = (gr0 < NN) ? dinv[gr0] : 0.f;
    const float dB = (gr1 < NN) ? dinv[gr1] : 0.f;
    const int cb = (t & 3) * 8;
    __syncthreads();

    for (int k0 = 0; k0 < 256; k0 += 32) {
        const int kb = k0 >> 5;
        int4 zz = {0, 0, 0, 0};
        int4 v0 = (gr0 < NN) ? *(const int4*)(x2 + (size_t)gr0 * 256 + k0 + cb) : zz;
        int4 v1 = (gr1 < NN) ? *(const int4*)(x2 + (size_t)gr1 * 256 + k0 + cb) : zz;
        const int c = k0 + cb;
        v0.x = bn2(v0.x, sSC[c + 0], sSH[c + 0], sSC[c + 1], sSH[c + 1], dA);
        v0.y = bn2(v0.y, sSC[c + 2], sSH[c + 2], sSC[c + 3], sSH[c + 3], dA);
        v0.z = bn2(v0.z, sSC[c + 4], sSH[c + 4], sSC[c + 5], sSH[c + 5], dA);
        v0.w = bn2(v0.w, sSC[c + 6], sSH[c + 6], sSC[c + 7], sSH[c + 7], dA);
        v1.x = bn2(v1.x, sSC[c + 0], sSH[c + 0], sSC[c + 1], sSH[c + 1], dB);
        v1.y = bn2(v1.y, sSC[c + 2], sSH[c + 2], sSC[c + 3], sSH[c + 3], dB);
        v1.z = bn2(v1.z, sSC[c + 4], sSH[c + 4], sSC[c + 5], sSH[c + 5], dB);
        v1.w = bn2(v1.w, sSC[c + 6], sSH[c + 6], sSC[c + 7], sSH[c + 7], dB);
        __syncthreads();
        *(int4*)&sA[t >> 2][cb] = v0;
        *(int4*)&sA[(t >> 2) + 64][cb] = v1;
        __syncthreads();
        size_t bo = ((size_t)(kb * 64 + w * 16 + l16)) * 32 + quad * 8;
        bf8 bh = *(const bf8*)(Wth + bo);
        bf8 bl = *(const bf8*)(Wtl + bo);
#pragma unroll
        for (int i = 0; i < 8; i++) {
            bf8 a = *(const bf8*)&sA[i * 16 + l16][quad * 8];
            acc[i] = __builtin_amdgcn_mfma_f32_16x16x32_bf16(a, bh, acc[i], 0, 0, 0);
            acc[i] = __builtin_amdgcn_mfma_f32_16x16x32_bf16(a, bl, acc[i], 0, 0, 0);
        }
    }
#pragma unroll
    for (int i = 0; i < 8; i++) {
#pragma unroll
        for (int r = 0; r < 4; r++) {
            float m = fabsf(acc[i][r]);
            m = fmaxf(m, __shfl_xor(m, 1));
            m = fmaxf(m, __shfl_xor(m, 2));
            m = fmaxf(m, __shfl_xor(m, 4));
            m = fmaxf(m, __shfl_xor(m, 8));
            if (l16 == 0) sM[i * 16 + quad * 4 + r][w] = m;
        }
    }
    __syncthreads();
    const int col = w * 16 + l16;
#pragma unroll
    for (int i = 0; i < 8; i++) {
#pragma unroll
        for (int r = 0; r < 4; r++) {
            int rloc = i * 16 + quad * 4 + r;
            int row = rowBase + rloc;
            float m = fmaxf(fmaxf(sM[rloc][0], sM[rloc][1]), fmaxf(sM[rloc][2], sM[rloc][3]));
            float inv = m > 0.f ? 127.f / m : 0.f;
            if (row < NN) {
                int q = (int)rintf(acc[i][r] * inv);
                H8[(size_t)row * 64 + col] = (unsigned char)(q & 0xff);
                if (w == 0 && l16 == 0) scaleH[row] = m * (1.f / 127.f);
            }
        }
    }
}

// ---- dual-row final aggregation from int8 H8 (64B rows) ----
__global__ __launch_bounds__(256) void k_aggfb2(const unsigned char* __restrict__ tab,
                                                const float* __restrict__ rscale,
                                                const float* __restrict__ dinv,
                                                const int* __restrict__ rowptr,
                                                const int* __restrict__ cnt,
                                                const int* __restrict__ csr,
                                                const float* __restrict__ bias,
                                                float* __restrict__ out) {
    const int wid = threadIdx.x >> 6;
    const int lane = threadIdx.x & 63;
    const int wstep = (blockDim.x >> 6) * gridDim.x;
    const int NP = (NN + 1) / 2;
    const float bv = (lane < FOUT) ? bias[lane] : 0.f;

    auto LOADB = [&](int row, int rp, int cn, int b, float* sc, int* u) {
#pragma unroll
        for (int j = 0; j < 8; j++) {
            int e = b * 8 + j;
            int ci = (e < cn) ? csr[rp + e] : row;
            sc[j] = (e < cn) ? rscale[ci] : 0.f;
            u[j] = (int)(signed char)tab[(size_t)ci * 64 + lane];
        }
    };
    auto FMAB = [&](float& acc, const float* sc, const int* u) {
#pragma unroll
        for (int j = 0; j < 8; j++) acc += sc[j] * (float)u[j];
    };

    for (int p0 = blockIdx.x * (blockDim.x >> 6) + wid; p0 < NP; p0 += wstep) {
        const int rA = __builtin_amdgcn_readfirstlane(p0 * 2);
        const int rB = min(rA + 1, NN - 1);
        const int rpA = __builtin_amdgcn_readfirstlane(rowptr[rA]);
        const int cnA = __builtin_amdgcn_readfirstlane(cnt[rA]);
        const int rpB = __builtin_amdgcn_readfirstlane(rowptr[rB]);
        const int cnB = __builtin_amdgcn_readfirstlane(cnt[rB]);
        float accA = rscale[rA] * (float)(int)(signed char)tab[(size_t)rA * 64 + lane];
        float accB = rscale[rB] * (float)(int)(signed char)tab[(size_t)rB * 64 + lane];
        const int nb = max((cnA + 7) >> 3, (cnB + 7) >> 3);
        if (nb > 0) {
            float scA0[8], scB0[8], scA1[8], scB1[8];
            int uA0[8], uB0[8], uA1[8], uB1[8];
            LOADB(rA, rpA, cnA, 0, scA0, uA0);
            LOADB(rB, rpB, cnB, 0, scB0, uB0);
            int b = 0;
            while (true) {
                bool more = (b + 1 < nb);
                if (more) LOADB(rA, rpA, cnA, b + 1, scA1, uA1);
                FMAB(accA, scA0, uA0);
                if (more) LOADB(rB, rpB, cnB, b + 1, scB1, uB1);
                FMAB(accB, scB0, uB0);
                if (!more) break;
                b++;
                bool more2 = (b + 1 < nb);
                if (more2) LOADB(rA, rpA, cnA, b + 1, scA0, uA0);
                FMAB(accA, scA1, uA1);
                if (more2) LOADB(rB, rpB, cnB, b + 1, scB0, uB0);
                FMAB(accB, scB1, uB1);
                if (!more2) break;
                b++;
            }
        }
        if (lane < FOUT) {
            out[(size_t)rA * FOUT + lane] = accA * dinv[rA] + bv;
            if (rB != rA) out[(size_t)rB * FOUT + lane] = accB * dinv[rB] + bv;
        }
    }
}

extern "C" void kernel_launch(void* const* d_in, const int* in_sizes, int n_in,
                              void* d_out, int out_size, void* d_ws, size_t ws_size,
                              hipStream_t stream) {
    const int* ei = (const int*)d_in[0];
    const float* z = (const float*)d_in[1];
    const float* W1 = (const float*)d_in[2];
    const float* b1 = (const float*)d_in[3];
    const float* g1 = (const float*)d_in[4];
    const float* be1 = (const float*)d_in[5];
    const float* W2 = (const float*)d_in[6];
    const float* b2 = (const float*)d_in[7];
    const float* g2 = (const float*)d_in[8];
    const float* be2 = (const float*)d_in[9];
    const float* W3 = (const float*)d_in[10];
    const float* b3 = (const float*)d_in[11];
    float* out = (float*)d_out;

    char* w = (char*)d_ws;
    size_t o = 0;
    auto take = [&](size_t bytes) {
        char* p = w + o;
        o = (o + bytes + 255) & ~(size_t)255;
        return p;
    };
    int* cnt = (int*)take((size_t)NN * 4);
    int* rowptr = (int*)take((size_t)NN * 4);
    int* gcur = (int*)take(NBKT * 4);
    int* bbase = (int*)take(NBKT * 4);
    int* csr = (int*)take((size_t)NE * 4 + 256);
    unsigned int* staging = (unsigned int*)take((size_t)NBKT * CAPB * 4);
    float* dinv = (float*)take((size_t)NN * 4);
    float* stat = (float*)take(4 * 256 * 4);
    unsigned short* Wt1h = (unsigned short*)take(256 * 128 * 2);
    unsigned short* Wt1l = (unsigned short*)take(256 * 128 * 2);
    unsigned short* Wt2h = (unsigned short*)take(256 * 256 * 2);
    unsigned short* Wt2l = (unsigned short*)take(256 * 256 * 2);
    unsigned short* Wt3h = (unsigned short*)take(64 * 256 * 2);
    unsigned short* Wt3l = (unsigned short*)take(64 * 256 * 2);
    unsigned char* zp8 = (unsigned char*)take((size_t)NN * FIN);
    unsigned char* y1_8 = (unsigned char*)take((size_t)NN * FH);
    unsigned char* H8 = (unsigned char*)take((size_t)NN * 64);
    float* scaleZ = (float*)take((size_t)NN * 4);
    float* scaleY = (float*)take((size_t)NN * 4);
    float* scaleH = (float*)take((size_t)NN * 4);
    unsigned short* P1 = (unsigned short*)take((size_t)NN * 256 * 2);
    unsigned short* P2 = (unsigned short*)take((size_t)NN * 512 * 2);

    unsigned short* a1 = P1;
    unsigned short* x1 = P2;
    unsigned short* a2 = P2 + (size_t)NN * 256;
    unsigned short* x2 = P1;
    float* s1a = stat, *s2a = stat + 256, *s1b = stat + 512, *s2b = stat + 768;

    hipMemsetAsync(gcur, 0, NBKT * 4, stream);
    hipMemsetAsync(stat, 0, 4 * 256 * 4, stream);

    // CSR build (two-level counting sort; dtype flag computed inline)
    k_bin<<<(NE + CHNK - 1) / CHNK, 256, 0, stream>>>(ei, gcur, staging);
    k_bucketscan<<<1, 256, 0, stream>>>(gcur, bbase);
    k_build<<<NBKT, 256, 0, stream>>>(staging, gcur, bbase, cnt, dinv, rowptr, csr);

    k_wprep<<<(256 * 128 + 256 * 256 + 64 * 256 + 255) / 256, 256, 0, stream>>>(
        W1, Wt1h, Wt1l, W2, Wt2h, Wt2l, W3, Wt3h, Wt3l);

    const int GR = (NN + 63) / 64;
    const int WV = (NN + 3) / 4;

    // layer 1
    k_zpb8<<<WV, 256, 0, stream>>>(z, dinv, zp8, scaleZ);
    k_agg2<128, true><<<2560, 256, 0, stream>>>(zp8, scaleZ, dinv, rowptr, cnt, csr, a1);
    k_gemm<128><<<dim3(2, GR), 256, 0, stream>>>(a1, Wt1h, Wt1l, b1, x1, s1a, s2a);
    k_bnr8<<<WV, 256, 0, stream>>>(x1, s1a, s2a, g1, be1, dinv, y1_8, scaleY);

    // layer 2
    k_agg2<256, false><<<2560, 256, 0, stream>>>(y1_8, scaleY, dinv, rowptr, cnt, csr, a2);
    k_gemm<256><<<dim3(2, GR), 256, 0, stream>>>(a2, Wt2h, Wt2l, b2, x2, s1b, s2b);

    // layer 3 (BN+ReLU fused into A-staging)
    k_mgemm3<<<NBKT, 256, 0, stream>>>(x2, s1b, s2b, g2, be2, Wt3h, Wt3l, dinv, H8, scaleH);
    k_aggfb2<<<2560, 256, 0, stream>>>(H8, scaleH, dinv, rowptr, cnt, csr, b3, out);
}

// Round 7
// 793.195 us; speedup vs baseline: 2.5687x; 1.2556x over previous
//
#include <hip/hip_runtime.h>

// GCN 3-layer: N=100000, E=3200000, 128 -> 256 -> 256 -> 40
// Round 14: consolidation. Gathers reverted to the round-8/r1 structure
// (scalar CSR walk, 8-edge batches) -- best verified at ~140us for the 256B
// table; six structural probes (VALU cut, instr packing x2, pipelining x2,
// L2 sharding, dual-row) all landed at or above it => random-line floor
// (~13 cy / 128B line / CU at saturated per-CU miss concurrency).
// Kept from r13: BN-stat fold into k_bnr8 and BN+ReLU+dinv fold into
// k_mgemm3 A-staging (kills 2 bnfold launches + k_bnr + ~100MB traffic).
// Agg grids 2048 = 8 blocks/CU exactly (tail-imbalance trim).
// Tables: zp signed i8 (128B rows), y1 unsigned i8 (256B), H3 signed i8 (64B).

#define NN   100000
#define NE   3200000
#define FIN  128
#define FH   256
#define FOUT 40
#define EPSV 1e-5f

#define BSH   7
#define NBKT  ((NN + 127) >> BSH)  // 782
#define CAPB  8192
#define CHNK  4096

typedef __attribute__((ext_vector_type(8))) short bf8;
typedef __attribute__((ext_vector_type(4))) float f32x4;

__device__ __forceinline__ unsigned short f2bf(float x) {
    unsigned int u = __float_as_uint(x);
    unsigned int r = u + 0x7fffu + ((u >> 16) & 1u);
    return (unsigned short)(r >> 16);
}
__device__ __forceinline__ float bf2f(unsigned short h) {
    return __uint_as_float(((unsigned int)h) << 16);
}
__device__ __forceinline__ void f2bf2(float x, unsigned short& hi, unsigned short& lo) {
    unsigned short h = f2bf(x);
    hi = h;
    lo = f2bf(x - bf2f(h));
}
__device__ __forceinline__ float ub(unsigned int u, int k) {
    return (float)((u >> (8 * k)) & 0xffu);
}
__device__ __forceinline__ float sbyte(unsigned int u, int k) {
    return (float)(int)(signed char)((u >> (8 * k)) & 0xffu);
}

// ---- pass 1: bin edges by dst>>7 into fixed-slot staging (flag computed inline) ----
__global__ __launch_bounds__(256) void k_bin(const int* __restrict__ ei,
                                             int* __restrict__ gcur,
                                             unsigned int* __restrict__ staging) {
    __shared__ int hcnt[NBKT];
    __shared__ int hbase[NBKT];
    __shared__ int sflag;
    const int tid = threadIdx.x;
    const int e0 = blockIdx.x * CHNK;
    for (int b = tid; b < NBKT; b += 256) hcnt[b] = 0;
    if (tid == 0) {
        int zz = 0;
        for (int i = 0; i < 64; i++) zz |= ei[2 * i + 1];
        sflag = (zz == 0) ? 1 : 0;
    }
    __syncthreads();
    const int f = sflag;
    for (int r = 0; r < CHNK / 256; r++) {
        int e = e0 + r * 256 + tid;
        if (e < NE) {
            int d = f ? ei[2 * (NE + e)] : ei[NE + e];
            atomicAdd(&hcnt[d >> BSH], 1);
        }
    }
    __syncthreads();
    for (int b = tid; b < NBKT; b += 256) {
        int c = hcnt[b];
        hbase[b] = c ? atomicAdd(&gcur[b], c) : 0;
    }
    __syncthreads();
    for (int b = tid; b < NBKT; b += 256) hcnt[b] = 0;
    __syncthreads();
    for (int r = 0; r < CHNK / 256; r++) {
        int e = e0 + r * 256 + tid;
        if (e < NE) {
            int s = f ? ei[2 * e] : ei[e];
            int d = f ? ei[2 * (NE + e)] : ei[NE + e];
            int b = d >> BSH;
            int loc = atomicAdd(&hcnt[b], 1);
            int pos = hbase[b] + loc;
            if (pos < CAPB)
                staging[(size_t)b * CAPB + pos] =
                    (unsigned int)s | ((unsigned int)(d & 127) << 17);
        }
    }
}

__global__ void k_bucketscan(const int* __restrict__ gcur, int* __restrict__ bbase) {
    __shared__ int sb2[2][256];
    int t = threadIdx.x;
    int base = t * 4;
    int v0 = (base + 0 < NBKT) ? gcur[base + 0] : 0;
    int v1 = (base + 1 < NBKT) ? gcur[base + 1] : 0;
    int v2 = (base + 2 < NBKT) ? gcur[base + 2] : 0;
    int v3 = (base + 3 < NBKT) ? gcur[base + 3] : 0;
    int s0 = v0, s1 = s0 + v1, s2 = s1 + v2, s3 = s2 + v3;
    sb2[0][t] = s3;
    __syncthreads();
    int pi = 0;
    for (int off = 1; off < 256; off <<= 1) {
        int x = sb2[pi][t];
        if (t >= off) x += sb2[pi][t - off];
        sb2[pi ^ 1][t] = x;
        __syncthreads();
        pi ^= 1;
    }
    int excl = sb2[pi][t] - s3;
    if (base + 0 < NBKT) bbase[base + 0] = excl;
    if (base + 1 < NBKT) bbase[base + 1] = excl + s0;
    if (base + 2 < NBKT) bbase[base + 2] = excl + s1;
    if (base + 3 < NBKT) bbase[base + 3] = excl + s2;
}

// ---- pass 2: per-bucket build of cnt/dinv/rowptr/csr ----
__global__ __launch_bounds__(256) void k_build(const unsigned int* __restrict__ staging,
                                               const int* __restrict__ gcur,
                                               const int* __restrict__ bbase,
                                               int* __restrict__ cntg,
                                               float* __restrict__ dinv,
                                               int* __restrict__ rowptr,
                                               int* __restrict__ csr) {
    __shared__ int lcnt[128];
    __shared__ int lscan[2][128];
    __shared__ int lcur[128];
    const int tid = threadIdx.x;
    const int b = blockIdx.x;
    const int tot = min(gcur[b], CAPB);
    const int bb = bbase[b];
    const unsigned int* st = staging + (size_t)b * CAPB;
    if (tid < 128) lcnt[tid] = 0;
    __syncthreads();
    for (int i = tid; i < tot; i += 256) {
        unsigned int v = st[i];
        atomicAdd(&lcnt[v >> 17], 1);
    }
    __syncthreads();
    int pi = 0;
    if (tid < 128) lscan[0][tid] = lcnt[tid];
    __syncthreads();
    for (int off = 1; off < 128; off <<= 1) {
        if (tid < 128) {
            int x = lscan[pi][tid];
            if (tid >= off) x += lscan[pi][tid - off];
            lscan[pi ^ 1][tid] = x;
        }
        __syncthreads();
        pi ^= 1;
    }
    if (tid < 128) {
        int c = lcnt[tid];
        int excl = lscan[pi][tid] - c;
        lcur[tid] = excl;
        int node = (b << BSH) + tid;
        if (node < NN) {
            cntg[node] = c;
            dinv[node] = rsqrtf((float)(c + 1));
            rowptr[node] = bb + excl;
        }
    }
    __syncthreads();
    for (int i = tid; i < tot; i += 256) {
        unsigned int v = st[i];
        int pos = atomicAdd(&lcur[v >> 17], 1);
        csr[bb + pos] = (int)(v & 0x1ffffu);
    }
}

// ---- fused weight prep: all three matrices, fragment-contiguous hi/lo bf16 ----
// Wt[((k>>5)*MP + m)*32 + (k&31)]
__global__ void k_wprep(const float* __restrict__ W1, unsigned short* __restrict__ W1h,
                        unsigned short* __restrict__ W1l,
                        const float* __restrict__ W2, unsigned short* __restrict__ W2h,
                        unsigned short* __restrict__ W2l,
                        const float* __restrict__ W3, unsigned short* __restrict__ W3h,
                        unsigned short* __restrict__ W3l) {
    int idx = blockIdx.x * blockDim.x + threadIdx.x;
    const float* W;
    unsigned short *Wh, *Wl;
    int K, M, MP;
    if (idx < 256 * 128) {
        W = W1; Wh = W1h; Wl = W1l; K = 128; M = 256; MP = 256;
    } else if (idx < 256 * 128 + 256 * 256) {
        idx -= 256 * 128;
        W = W2; Wh = W2h; Wl = W2l; K = 256; M = 256; MP = 256;
    } else if (idx < 256 * 128 + 256 * 256 + 64 * 256) {
        idx -= 256 * 128 + 256 * 256;
        W = W3; Wh = W3h; Wl = W3l; K = 256; M = 40; MP = 64;
    } else {
        return;
    }
    int m = idx / K, k = idx - m * K;
    float v = (m < M) ? W[(size_t)k * M + m] : 0.f;
    unsigned short h, l;
    f2bf2(v, h, l);
    size_t dst = ((size_t)(k >> 5) * MP + m) * 32 + (k & 31);
    Wh[dst] = h;
    Wl[dst] = l;
}

// ---- z * dinv -> signed int8 rows + per-row scale (wave per row) ----
__global__ __launch_bounds__(256) void k_zpb8(const float* __restrict__ z,
                                              const float* __restrict__ dinv,
                                              unsigned char* __restrict__ zp8,
                                              float* __restrict__ scaleZ) {
    int wv = (blockIdx.x * blockDim.x + threadIdx.x) >> 6;
    int lane = threadIdx.x & 63;
    if (wv >= NN) return;
    float2 v = *(const float2*)(z + (size_t)wv * FIN + lane * 2);
    float d = dinv[wv];
    float a0 = v.x * d, a1 = v.y * d;
    float m = fmaxf(fabsf(a0), fabsf(a1));
#pragma unroll
    for (int off = 1; off < 64; off <<= 1) m = fmaxf(m, __shfl_xor(m, off));
    float inv = m > 0.f ? 127.f / m : 0.f;
    int q0 = (int)rintf(a0 * inv), q1 = (int)rintf(a1 * inv);
    unsigned short pk = (unsigned short)((q0 & 0xff) | ((q1 & 0xff) << 8));
    *(unsigned short*)(zp8 + (size_t)wv * FIN + lane * 2) = pk;
    if (lane == 0) scaleZ[wv] = m * (1.f / 127.f);
}

// ---- BN(from stats)+ReLU+dinv -> unsigned int8 rows + per-row scale ----
__global__ __launch_bounds__(256) void k_bnr8(const unsigned short* __restrict__ x,
                                              const float* __restrict__ s1,
                                              const float* __restrict__ s2,
                                              const float* __restrict__ g,
                                              const float* __restrict__ be,
                                              const float* __restrict__ dinv,
                                              unsigned char* __restrict__ y8,
                                              float* __restrict__ scaleY) {
    int wv = (blockIdx.x * blockDim.x + threadIdx.x) >> 6;
    int lane = threadIdx.x & 63;
    if (wv >= NN) return;
    float4 m1 = *(const float4*)(s1 + lane * 4);
    float4 m2 = *(const float4*)(s2 + lane * 4);
    float4 gg = *(const float4*)(g + lane * 4);
    float4 bb = *(const float4*)(be + lane * 4);
    float mx = m1.x * (1.f / NN), my = m1.y * (1.f / NN);
    float mz = m1.z * (1.f / NN), mw = m1.w * (1.f / NN);
    float scx = gg.x * rsqrtf(m2.x * (1.f / NN) - mx * mx + EPSV);
    float scy = gg.y * rsqrtf(m2.y * (1.f / NN) - my * my + EPSV);
    float scz = gg.z * rsqrtf(m2.z * (1.f / NN) - mz * mz + EPSV);
    float scw = gg.w * rsqrtf(m2.w * (1.f / NN) - mw * mw + EPSV);
    float shx = bb.x - mx * scx, shy = bb.y - my * scy;
    float shz = bb.z - mz * scz, shw = bb.w - mw * scw;
    uint2 u = *(const uint2*)(x + (size_t)wv * 256 + lane * 4);
    float d = dinv[wv];
    float v0 = fmaxf(__uint_as_float(u.x << 16) * scx + shx, 0.f) * d;
    float v1 = fmaxf(__uint_as_float(u.x & 0xffff0000u) * scy + shy, 0.f) * d;
    float v2 = fmaxf(__uint_as_float(u.y << 16) * scz + shz, 0.f) * d;
    float v3 = fmaxf(__uint_as_float(u.y & 0xffff0000u) * scw + shw, 0.f) * d;
    float m = fmaxf(fmaxf(v0, v1), fmaxf(v2, v3));
#pragma unroll
    for (int off = 1; off < 64; off <<= 1) m = fmaxf(m, __shfl_xor(m, off));
    float inv = m > 0.f ? 255.f / m : 0.f;
    unsigned int q0 = (unsigned int)(v0 * inv + 0.5f);
    unsigned int q1 = (unsigned int)(v1 * inv + 0.5f);
    unsigned int q2 = (unsigned int)(v2 * inv + 0.5f);
    unsigned int q3 = (unsigned int)(v3 * inv + 0.5f);
    *(unsigned int*)(y8 + (size_t)wv * 256 + lane * 4) = q0 | (q1 << 8) | (q2 << 16) | (q3 << 24);
    if (lane == 0) scaleY[wv] = m * (1.f / 255.f);
}

// ---- int8 gather aggregation, scalarized CSR walk (r1 structure, verified best) ----
// F=128: signed, ushort/lane; F=256: unsigned, uint/lane.
template <int F, bool SIGNED>
__global__ __launch_bounds__(256) void k_agg8(const unsigned char* __restrict__ tab,
                                              const float* __restrict__ rscale,
                                              const float* __restrict__ dinv,
                                              const int* __restrict__ rowptr,
                                              const int* __restrict__ cnt,
                                              const int* __restrict__ csr,
                                              unsigned short* __restrict__ oa) {
    const int wid = threadIdx.x >> 6;
    const int lane = threadIdx.x & 63;
    const int wstep = (blockDim.x >> 6) * gridDim.x;
    constexpr int B = F / 64;
    const int off = lane * B;
    for (int row0 = blockIdx.x * (blockDim.x >> 6) + wid; row0 < NN; row0 += wstep) {
        const int row = __builtin_amdgcn_readfirstlane(row0);
        const int rp = __builtin_amdgcn_readfirstlane(rowptr[row]);
        const int cn = __builtin_amdgcn_readfirstlane(cnt[row]);
        float acc[B];
        {
            float s = rscale[row];
            if constexpr (B == 4) {
                unsigned int u = *(const unsigned int*)(tab + (size_t)row * F + off);
                acc[0] = s * ub(u, 0); acc[1] = s * ub(u, 1);
                acc[2] = s * ub(u, 2); acc[3] = s * ub(u, 3);
            } else {
                unsigned int u = *(const unsigned short*)(tab + (size_t)row * F + off);
                acc[0] = s * sbyte(u, 0); acc[1] = s * sbyte(u, 1);
            }
        }
        int e = 0;
        for (; e + 8 <= cn; e += 8) {
            int idx[8];
            float s[8];
            unsigned int u[8];
#pragma unroll
            for (int j = 0; j < 8; j++) idx[j] = csr[rp + e + j];
#pragma unroll
            for (int j = 0; j < 8; j++) s[j] = rscale[idx[j]];
#pragma unroll
            for (int j = 0; j < 8; j++) {
                if constexpr (B == 4)
                    u[j] = *(const unsigned int*)(tab + (size_t)idx[j] * F + off);
                else
                    u[j] = *(const unsigned short*)(tab + (size_t)idx[j] * F + off);
            }
#pragma unroll
            for (int j = 0; j < 8; j++) {
                if constexpr (B == 4) {
                    acc[0] += s[j] * ub(u[j], 0); acc[1] += s[j] * ub(u[j], 1);
                    acc[2] += s[j] * ub(u[j], 2); acc[3] += s[j] * ub(u[j], 3);
                } else {
                    acc[0] += s[j] * sbyte(u[j], 0); acc[1] += s[j] * sbyte(u[j], 1);
                }
            }
        }
        for (; e < cn; e++) {
            int idx = csr[rp + e];
            float s = rscale[idx];
            if constexpr (B == 4) {
                unsigned int u = *(const unsigned int*)(tab + (size_t)idx * F + off);
                acc[0] += s * ub(u, 0); acc[1] += s * ub(u, 1);
                acc[2] += s * ub(u, 2); acc[3] += s * ub(u, 3);
            } else {
                unsigned int u = *(const unsigned short*)(tab + (size_t)idx * F + off);
                acc[0] += s * sbyte(u, 0); acc[1] += s * sbyte(u, 1);
            }
        }
        float d = dinv[row];
        size_t p = (size_t)row * F + off;
        if constexpr (B == 4) {
            uint2 o;
            o.x = (unsigned int)f2bf(acc[0] * d) | ((unsigned int)f2bf(acc[1] * d) << 16);
            o.y = (unsigned int)f2bf(acc[2] * d) | ((unsigned int)f2bf(acc[3] * d) << 16);
            *(uint2*)(oa + p) = o;
        } else {
            *(unsigned int*)(oa + p) =
                (unsigned int)f2bf(acc[0] * d) | ((unsigned int)f2bf(acc[1] * d) << 16);
        }
    }
}

// ---- GEMM: 64-row x 128-col tile; A bf16, W hi/lo; bias + BN stats fused ----
template <int K>
__global__ __launch_bounds__(256) void k_gemm(const unsigned short* __restrict__ A,
                                              const unsigned short* __restrict__ Wth,
                                              const unsigned short* __restrict__ Wtl,
                                              const float* __restrict__ bias,
                                              unsigned short* __restrict__ outX,
                                              float* __restrict__ s1,
                                              float* __restrict__ s2) {
    __shared__ unsigned short sA[64][40];
    const int t = threadIdx.x;
    const int w = t >> 6, lane = t & 63;
    const int quad = lane >> 4, l16 = lane & 15;
    const int rowBase = blockIdx.y * 64;
    const int colW = blockIdx.x * 128 + w * 32;
    f32x4 acc[4][2];
#pragma unroll
    for (int i = 0; i < 4; i++)
#pragma unroll
        for (int j = 0; j < 2; j++) acc[i][j] = (f32x4)0.f;

    for (int k0 = 0; k0 < K; k0 += 32) {
        int gr = rowBase + (t >> 2);
        int4 v = {0, 0, 0, 0};
        if (gr < NN) v = *(const int4*)(A + (size_t)gr * K + k0 + (t & 3) * 8);
        __syncthreads();
        *(int4*)&sA[t >> 2][(t & 3) * 8] = v;
        __syncthreads();
        const int kb = k0 >> 5;
        bf8 bh[2], bl[2];
#pragma unroll
        for (int j = 0; j < 2; j++) {
            size_t bo = ((size_t)(kb * 256 + colW + j * 16 + l16)) * 32 + quad * 8;
            bh[j] = *(const bf8*)(Wth + bo);
            bl[j] = *(const bf8*)(Wtl + bo);
        }
#pragma unroll
        for (int i = 0; i < 4; i++) {
            bf8 a = *(const bf8*)&sA[i * 16 + l16][quad * 8];
#pragma unroll
            for (int j = 0; j < 2; j++) {
                acc[i][j] = __builtin_amdgcn_mfma_f32_16x16x32_bf16(a, bh[j], acc[i][j], 0, 0, 0);
                acc[i][j] = __builtin_amdgcn_mfma_f32_16x16x32_bf16(a, bl[j], acc[i][j], 0, 0, 0);
            }
        }
    }
#pragma unroll
    for (int j = 0; j < 2; j++) {
        int col = colW + j * 16 + l16;
        float b = bias[col];
        float s1p = 0.f, s2p = 0.f;
#pragma unroll
        for (int i = 0; i < 4; i++) {
#pragma unroll
            for (int r = 0; r < 4; r++) {
                int row = rowBase + i * 16 + quad * 4 + r;
                if (row < NN) {
                    float v = acc[i][j][r] + b;
                    s1p += v;
                    s2p += v * v;
                    outX[(size_t)row * 256 + col] = f2bf(v);
                }
            }
        }
        s1p += __shfl_xor(s1p, 16); s1p += __shfl_xor(s1p, 32);
        s2p += __shfl_xor(s2p, 16); s2p += __shfl_xor(s2p, 32);
        if (quad == 0) {
            atomicAdd(&s1[col], s1p);
            atomicAdd(&s2[col], s2p);
        }
    }
}

__device__ __forceinline__ unsigned int bn2(unsigned int w, float sc0, float sh0,
                                            float sc1, float sh1, float d) {
    float x0 = __uint_as_float(w << 16);
    float x1 = __uint_as_float(w & 0xffff0000u);
    float y0 = fmaxf(x0 * sc0 + sh0, 0.f) * d;
    float y1 = fmaxf(x1 * sc1 + sh1, 0.f) * d;
    return (unsigned int)f2bf(y0) | ((unsigned int)f2bf(y1) << 16);
}

// ---- layer-3 GEMM with fused BN+ReLU on A-staging -> signed int8 H3 + scale ----
__global__ __launch_bounds__(256) void k_mgemm3(const unsigned short* __restrict__ x2,
                                                const float* __restrict__ s1,
                                                const float* __restrict__ s2,
                                                const float* __restrict__ g,
                                                const float* __restrict__ be,
                                                const unsigned short* __restrict__ Wth,
                                                const unsigned short* __restrict__ Wtl,
                                                const float* __restrict__ dinv,
                                                unsigned char* __restrict__ H8,
                                                float* __restrict__ scaleH) {
    __shared__ unsigned short sA[128][40];
    __shared__ float sM[128][4];
    __shared__ float sSC[256];
    __shared__ float sSH[256];
    const int t = threadIdx.x;
    const int w = t >> 6, lane = t & 63;
    const int quad = lane >> 4, l16 = lane & 15;
    const int rowBase = blockIdx.x << 7;
    {
        float mean = s1[t] * (1.f / NN);
        float var = s2[t] * (1.f / NN) - mean * mean;
        float sc = g[t] * rsqrtf(var + EPSV);
        sSC[t] = sc;
        sSH[t] = be[t] - mean * sc;
    }
    f32x4 acc[8];
#pragma unroll
    for (int i = 0; i < 8; i++) acc[i] = (f32x4)0.f;

    const int gr0 = rowBase + (t >> 2);
    const int gr1 = gr0 + 64;
    const float dA = (gr0 < NN) ? dinv[gr0] : 0.f;
    const float dB = (gr1 < NN) ? dinv[gr1] : 0.f;
    const int cb = (t & 3) * 8;
    __syncthreads();

    for (int k0 = 0; k0 < 256; k0 += 32) {
        const int kb = k0 >> 5;
        int4 zz = {0, 0, 0, 0};
        int4 v0 = (gr0 < NN) ? *(const int4*)(x2 + (size_t)gr0 * 256 + k0 + cb) : zz;
        int4 v1 = (gr1 < NN) ? *(const int4*)(x2 + (size_t)gr1 * 256 + k0 + cb) : zz;
        const int c = k0 + cb;
        v0.x = bn2(v0.x, sSC[c + 0], sSH[c + 0], sSC[c + 1], sSH[c + 1], dA);
        v0.y = bn2(v0.y, sSC[c + 2], sSH[c + 2], sSC[c + 3], sSH[c + 3], dA);
        v0.z = bn2(v0.z, sSC[c + 4], sSH[c + 4], sSC[c + 5], sSH[c + 5], dA);
        v0.w = bn2(v0.w, sSC[c + 6], sSH[c + 6], sSC[c + 7], sSH[c + 7], dA);
        v1.x = bn2(v1.x, sSC[c + 0], sSH[c + 0], sSC[c + 1], sSH[c + 1], dB);
        v1.y = bn2(v1.y, sSC[c + 2], sSH[c + 2], sSC[c + 3], sSH[c + 3], dB);
        v1.z = bn2(v1.z, sSC[c + 4], sSH[c + 4], sSC[c + 5], sSH[c + 5], dB);
        v1.w = bn2(v1.w, sSC[c + 6], sSH[c + 6], sSC[c + 7], sSH[c + 7], dB);
        __syncthreads();
        *(int4*)&sA[t >> 2][cb] = v0;
        *(int4*)&sA[(t >> 2) + 64][cb] = v1;
        __syncthreads();
        size_t bo = ((size_t)(kb * 64 + w * 16 + l16)) * 32 + quad * 8;
        bf8 bh = *(const bf8*)(Wth + bo);
        bf8 bl = *(const bf8*)(Wtl + bo);
#pragma unroll
        for (int i = 0; i < 8; i++) {
            bf8 a = *(const bf8*)&sA[i * 16 + l16][quad * 8];
            acc[i] = __builtin_amdgcn_mfma_f32_16x16x32_bf16(a, bh, acc[i], 0, 0, 0);
            acc[i] = __builtin_amdgcn_mfma_f32_16x16x32_bf16(a, bl, acc[i], 0, 0, 0);
        }
    }
#pragma unroll
    for (int i = 0; i < 8; i++) {
#pragma unroll
        for (int r = 0; r < 4; r++) {
            float m = fabsf(acc[i][r]);
            m = fmaxf(m, __shfl_xor(m, 1));
            m = fmaxf(m, __shfl_xor(m, 2));
            m = fmaxf(m, __shfl_xor(m, 4));
            m = fmaxf(m, __shfl_xor(m, 8));
            if (l16 == 0) sM[i * 16 + quad * 4 + r][w] = m;
        }
    }
    __syncthreads();
    const int col = w * 16 + l16;
#pragma unroll
    for (int i = 0; i < 8; i++) {
#pragma unroll
        for (int r = 0; r < 4; r++) {
            int rloc = i * 16 + quad * 4 + r;
            int row = rowBase + rloc;
            float m = fmaxf(fmaxf(sM[rloc][0], sM[rloc][1]), fmaxf(sM[rloc][2], sM[rloc][3]));
            float inv = m > 0.f ? 127.f / m : 0.f;
            if (row < NN) {
                int q = (int)rintf(acc[i][r] * inv);
                H8[(size_t)row * 64 + col] = (unsigned char)(q & 0xff);
                if (w == 0 && l16 == 0) scaleH[row] = m * (1.f / 127.f);
            }
        }
    }
}

// ---- final aggregation from int8 H8 (64B rows), scalarized CSR walk ----
__global__ __launch_bounds__(256) void k_aggfb8(const unsigned char* __restrict__ tab,
                                                const float* __restrict__ rscale,
                                                const float* __restrict__ dinv,
                                                const int* __restrict__ rowptr,
                                                const int* __restrict__ cnt,
                                                const int* __restrict__ csr,
                                                const float* __restrict__ bias,
                                                float* __restrict__ out) {
    const int wid = threadIdx.x >> 6;
    const int lane = threadIdx.x & 63;
    const int wstep = (blockDim.x >> 6) * gridDim.x;
    for (int row0 = blockIdx.x * (blockDim.x >> 6) + wid; row0 < NN; row0 += wstep) {
        const int row = __builtin_amdgcn_readfirstlane(row0);
        const int rp = __builtin_amdgcn_readfirstlane(rowptr[row]);
        const int cn = __builtin_amdgcn_readfirstlane(cnt[row]);
        float acc = rscale[row] * (float)(int)(signed char)tab[(size_t)row * 64 + lane];
        int e = 0;
        for (; e + 8 <= cn; e += 8) {
            int idx[8];
            float s[8];
            float v[8];
#pragma unroll
            for (int j = 0; j < 8; j++) idx[j] = csr[rp + e + j];
#pragma unroll
            for (int j = 0; j < 8; j++) s[j] = rscale[idx[j]];
#pragma unroll
            for (int j = 0; j < 8; j++)
                v[j] = (float)(int)(signed char)tab[(size_t)idx[j] * 64 + lane];
#pragma unroll
            for (int j = 0; j < 8; j++) acc += s[j] * v[j];
        }
        for (; e < cn; e++) {
            int idx = csr[rp + e];
            float s = rscale[idx];
            acc += s * (float)(int)(signed char)tab[(size_t)idx * 64 + lane];
        }
        if (lane < FOUT) out[(size_t)row * FOUT + lane] = acc * dinv[row] + bias[lane];
    }
}

extern "C" void kernel_launch(void* const* d_in, const int* in_sizes, int n_in,
                              void* d_out, int out_size, void* d_ws, size_t ws_size,
                              hipStream_t stream) {
    const int* ei = (const int*)d_in[0];
    const float* z = (const float*)d_in[1];
    const float* W1 = (const float*)d_in[2];
    const float* b1 = (const float*)d_in[3];
    const float* g1 = (const float*)d_in[4];
    const float* be1 = (const float*)d_in[5];
    const float* W2 = (const float*)d_in[6];
    const float* b2 = (const float*)d_in[7];
    const float* g2 = (const float*)d_in[8];
    const float* be2 = (const float*)d_in[9];
    const float* W3 = (const float*)d_in[10];
    const float* b3 = (const float*)d_in[11];
    float* out = (float*)d_out;

    char* w = (char*)d_ws;
    size_t o = 0;
    auto take = [&](size_t bytes) {
        char* p = w + o;
        o = (o + bytes + 255) & ~(size_t)255;
        return p;
    };
    int* cnt = (int*)take((size_t)NN * 4);
    int* rowptr = (int*)take((size_t)NN * 4);
    int* gcur = (int*)take(NBKT * 4);
    int* bbase = (int*)take(NBKT * 4);
    int* csr = (int*)take((size_t)NE * 4 + 256);
    unsigned int* staging = (unsigned int*)take((size_t)NBKT * CAPB * 4);
    float* dinv = (float*)take((size_t)NN * 4);
    float* stat = (float*)take(4 * 256 * 4);
    unsigned short* Wt1h = (unsigned short*)take(256 * 128 * 2);
    unsigned short* Wt1l = (unsigned short*)take(256 * 128 * 2);
    unsigned short* Wt2h = (unsigned short*)take(256 * 256 * 2);
    unsigned short* Wt2l = (unsigned short*)take(256 * 256 * 2);
    unsigned short* Wt3h = (unsigned short*)take(64 * 256 * 2);
    unsigned short* Wt3l = (unsigned short*)take(64 * 256 * 2);
    unsigned char* zp8 = (unsigned char*)take((size_t)NN * FIN);
    unsigned char* y1_8 = (unsigned char*)take((size_t)NN * FH);
    unsigned char* H8 = (unsigned char*)take((size_t)NN * 64);
    float* scaleZ = (float*)take((size_t)NN * 4);
    float* scaleY = (float*)take((size_t)NN * 4);
    float* scaleH = (float*)take((size_t)NN * 4);
    unsigned short* P1 = (unsigned short*)take((size_t)NN * 256 * 2);
    unsigned short* P2 = (unsigned short*)take((size_t)NN * 512 * 2);

    unsigned short* a1 = P1;
    unsigned short* x1 = P2;
    unsigned short* a2 = P2 + (size_t)NN * 256;
    unsigned short* x2 = P1;
    float* s1a = stat, *s2a = stat + 256, *s1b = stat + 512, *s2b = stat + 768;

    hipMemsetAsync(gcur, 0, NBKT * 4, stream);
    hipMemsetAsync(stat, 0, 4 * 256 * 4, stream);

    // CSR build (two-level counting sort; dtype flag computed inline)
    k_bin<<<(NE + CHNK - 1) / CHNK, 256, 0, stream>>>(ei, gcur, staging);
    k_bucketscan<<<1, 256, 0, stream>>>(gcur, bbase);
    k_build<<<NBKT, 256, 0, stream>>>(staging, gcur, bbase, cnt, dinv, rowptr, csr);

    k_wprep<<<(256 * 128 + 256 * 256 + 64 * 256 + 255) / 256, 256, 0, stream>>>(
        W1, Wt1h, Wt1l, W2, Wt2h, Wt2l, W3, Wt3h, Wt3l);

    const int GR = (NN + 63) / 64;
    const int WV = (NN + 3) / 4;

    // layer 1
    k_zpb8<<<WV, 256, 0, stream>>>(z, dinv, zp8, scaleZ);
    k_agg8<128, true><<<2048, 256, 0, stream>>>(zp8, scaleZ, dinv, rowptr, cnt, csr, a1);
    k_gemm<128><<<dim3(2, GR), 256, 0, stream>>>(a1, Wt1h, Wt1l, b1, x1, s1a, s2a);
    k_bnr8<<<WV, 256, 0, stream>>>(x1, s1a, s2a, g1, be1, dinv, y1_8, scaleY);

    // layer 2
    k_agg8<256, false><<<2048, 256, 0, stream>>>(y1_8, scaleY, dinv, rowptr, cnt, csr, a2);
    k_gemm<256><<<dim3(2, GR), 256, 0, stream>>>(a2, Wt2h, Wt2l, b2, x2, s1b, s2b);

    // layer 3 (BN+ReLU+dinv fused into A-staging)
    k_mgemm3<<<NBKT, 256, 0, stream>>>(x2, s1b, s2b, g2, be2, Wt3h, Wt3l, dinv, H8, scaleH);
    k_aggfb8<<<2048, 256, 0, stream>>>(H8, scaleH, dinv, rowptr, cnt, csr, b3, out);
}